// Round 5
// baseline (905.410 us; speedup 1.0000x reference)
//
#include <hip/hip_runtime.h>
#include <hip/hip_bf16.h>

typedef __bf16 bf16_t;
typedef bf16_t bf16x8 __attribute__((ext_vector_type(8)));
typedef bf16_t bf16x4 __attribute__((ext_vector_type(4)));
typedef float f32x4 __attribute__((ext_vector_type(4)));

typedef const __attribute__((address_space(1))) void GV;
typedef __attribute__((address_space(3))) void LV;

__device__ __forceinline__ void gload_lds16(const bf16_t* gsrc, bf16_t* ldst) {
    __builtin_amdgcn_global_load_lds((GV*)gsrc, (LV*)ldst, 16, 0, 0);
}

// ---------------- weight transpose+convert: in fp32 (K x N) -> out bf16 (N x K)
__global__ __launch_bounds__(256) void wtrans_kernel(const float* __restrict__ in,
                                                     bf16_t* __restrict__ out, int K, int N)
{
    __shared__ float tile[32][33];
    const int n0 = blockIdx.x * 32, k0 = blockIdx.y * 32;
    const int tx = threadIdx.x & 31, ty = threadIdx.x >> 5;  // 32 x 8
#pragma unroll
    for (int i = 0; i < 32; i += 8)
        tile[ty + i][tx] = in[(long long)(k0 + ty + i) * N + n0 + tx];
    __syncthreads();
#pragma unroll
    for (int i = 0; i < 32; i += 8)
        out[(long long)(n0 + ty + i) * K + k0 + tx] = (bf16_t)tile[tx][ty + i];
}

// ---------------- 6 modulation linears on cond: out[(sig*8+b)*512 + n]
__global__ __launch_bounds__(256) void modsig_kernel(
    const float* __restrict__ cond,
    const float* __restrict__ w0, const float* __restrict__ w1, const float* __restrict__ w2,
    const float* __restrict__ w3, const float* __restrict__ w4, const float* __restrict__ w5,
    const float* __restrict__ c0, const float* __restrict__ c1, const float* __restrict__ c2,
    const float* __restrict__ c3, const float* __restrict__ c4, const float* __restrict__ c5,
    float* __restrict__ out)
{
    __shared__ float cs[512];
    const int sig = blockIdx.x >> 3, b = blockIdx.x & 7;
    const float* w; const float* bi;
    switch (sig) {
        case 0: w = w0; bi = c0; break;
        case 1: w = w1; bi = c1; break;
        case 2: w = w2; bi = c2; break;
        case 3: w = w3; bi = c3; break;
        case 4: w = w4; bi = c4; break;
        default: w = w5; bi = c5; break;
    }
    for (int i = threadIdx.x; i < 512; i += 256) cs[i] = cond[b * 512 + i];
    __syncthreads();
    for (int n = threadIdx.x; n < 512; n += 256) {
        float s = bi[n];
        for (int i = 0; i < 512; ++i) s = fmaf(cs[i], w[(long long)i * 512 + n], s);
        out[(long long)(sig * 8 + b) * 512 + n] = s;
    }
}

// ---------------- fused LayerNorm + AdaLN modulate, fp32 -> bf16
__global__ __launch_bounds__(128) void ln_mod_kernel(
    const float* __restrict__ x, const float* __restrict__ g, const float* __restrict__ be,
    const float* __restrict__ gamma, const float* __restrict__ beta, bf16_t* __restrict__ out)
{
    const int row = blockIdx.x;
    const int b = row >> 10;
    const int t = threadIdx.x;
    const float4 v = reinterpret_cast<const float4*>(x + (long long)row * 512)[t];
    float s = v.x + v.y + v.z + v.w;
    float ss = v.x * v.x + v.y * v.y + v.z * v.z + v.w * v.w;
    for (int o = 32; o; o >>= 1) { s += __shfl_xor(s, o); ss += __shfl_xor(ss, o); }
    __shared__ float red[4];
    if ((t & 63) == 0) { red[t >> 6] = s; red[2 + (t >> 6)] = ss; }
    __syncthreads();
    s = red[0] + red[1]; ss = red[2] + red[3];
    const float mu = s * (1.f / 512.f);
    const float rstd = rsqrtf(ss * (1.f / 512.f) - mu * mu + 1e-5f);
    const float4 gv = reinterpret_cast<const float4*>(g)[t];
    const float4 bv = reinterpret_cast<const float4*>(be)[t];
    const float4 ga = reinterpret_cast<const float4*>(gamma + b * 512)[t];
    const float4 bb = reinterpret_cast<const float4*>(beta + b * 512)[t];
    bf16x4 ov;
    ov[0] = (bf16_t)(((v.x - mu) * rstd * gv.x + bv.x) * (1.f + ga.x) + bb.x);
    ov[1] = (bf16_t)(((v.y - mu) * rstd * gv.y + bv.y) * (1.f + ga.y) + bb.y);
    ov[2] = (bf16_t)(((v.z - mu) * rstd * gv.z + bv.z) * (1.f + ga.z) + bb.z);
    ov[3] = (bf16_t)(((v.w - mu) * rstd * gv.w + bv.w) * (1.f + ga.w) + bb.w);
    reinterpret_cast<bf16x4*>(out + (long long)row * 512)[t] = ov;
}

// ---------------- 128x128x32 bf16 MFMA GEMM via global_load_lds, C = A * B^T
// EPI 1: relu->bf16 (+bias)   (other EPIs retained for completeness)
template <int EPI>
__global__ __launch_bounds__(256) void gemm128_kernel(
    const bf16_t* __restrict__ A, const bf16_t* __restrict__ B,
    const float* __restrict__ bias, void* Cout,
    int M, int N, int K, int lda, int ldb, int ldc)
{
    const int m0 = blockIdx.y * 128, n0 = blockIdx.x * 128;
    const int tid = threadIdx.x, lane = tid & 63, wid = tid >> 6;
    const int wr = wid >> 1, wc = wid & 1;

    __shared__ bf16_t As[4096];
    __shared__ bf16_t Bs[4096];

    f32x4 acc[4][4];
#pragma unroll
    for (int m = 0; m < 4; ++m)
#pragma unroll
        for (int n = 0; n < 4; ++n) acc[m][n] = (f32x4){0.f, 0.f, 0.f, 0.f};

    const int r0 = wid * 16 + (lane >> 2);
    const int lc = (lane & 3) ^ ((lane >> 2) & 3);
    const long long aOff0 = (long long)(m0 + r0) * lda + lc * 8;
    const long long aOff1 = (long long)(m0 + r0 + 64) * lda + lc * 8;
    const long long bOff0 = (long long)(n0 + r0) * ldb + lc * 8;
    const long long bOff1 = (long long)(n0 + r0 + 64) * ldb + lc * 8;
    bf16_t* aDst0 = As + wid * 512;
    bf16_t* aDst1 = As + 2048 + wid * 512;
    bf16_t* bDst0 = Bs + wid * 512;
    bf16_t* bDst1 = Bs + 2048 + wid * 512;

    const int frow = lane & 15, lg = lane >> 4;
    const int pc = lg ^ (frow & 3);

    for (int kt = 0; kt < K; kt += 32) {
        gload_lds16(A + aOff0 + kt, aDst0);
        gload_lds16(A + aOff1 + kt, aDst1);
        gload_lds16(B + bOff0 + kt, bDst0);
        gload_lds16(B + bOff1 + kt, bDst1);
        __syncthreads();
        bf16x8 af[4], bfv[4];
#pragma unroll
        for (int m = 0; m < 4; ++m)
            af[m] = *reinterpret_cast<const bf16x8*>(As + (wr * 64 + m * 16 + frow) * 32 + pc * 8);
#pragma unroll
        for (int n = 0; n < 4; ++n)
            bfv[n] = *reinterpret_cast<const bf16x8*>(Bs + (wc * 64 + n * 16 + frow) * 32 + pc * 8);
        __builtin_amdgcn_s_setprio(1);
#pragma unroll
        for (int m = 0; m < 4; ++m)
#pragma unroll
            for (int n = 0; n < 4; ++n)
                acc[m][n] = __builtin_amdgcn_mfma_f32_16x16x32_bf16(af[m], bfv[n], acc[m][n], 0, 0, 0);
        __builtin_amdgcn_s_setprio(0);
        __syncthreads();
    }

#pragma unroll
    for (int m = 0; m < 4; ++m) {
        const int gm = m0 + wr * 64 + m * 16 + ((lane >> 4) << 2);
#pragma unroll
        for (int n = 0; n < 4; ++n) {
            const int gn = n0 + wc * 64 + n * 16 + (lane & 15);
            const float bb = bias ? bias[gn] : 0.f;
#pragma unroll
            for (int j = 0; j < 4; ++j) {
                const float v = acc[m][n][j] + bb;
                const int gmj = gm + j;
                if (EPI == 0) {
                    ((bf16_t*)Cout)[(long long)gmj * ldc + gn] = (bf16_t)v;
                } else if (EPI == 1) {
                    ((bf16_t*)Cout)[(long long)gmj * ldc + gn] = (bf16_t)fmaxf(v, 0.f);
                } else {
                    const long long ci =
                        (long long)(((gmj >> 10) * 8 + (gn >> 9)) * 512 + (gn & 511)) * 1024 + (gmj & 1023);
                    ((bf16_t*)Cout)[ci] = (bf16_t)v;
                }
            }
        }
    }
}

// ---------------- fused QKV GEMM: B = [wqT;wkT;wvT] (12288 x 512 contiguous)
// n-section 0 -> qb, 1 -> kb (qkv+33554432), 2 -> vtb (transposed-V layout)
__global__ __launch_bounds__(256) void gemmqkv_kernel(
    const bf16_t* __restrict__ A, const bf16_t* __restrict__ B,
    const float* __restrict__ bq, const float* __restrict__ bk, const float* __restrict__ bv,
    bf16_t* __restrict__ qkv, bf16_t* __restrict__ vtb)
{
    const int m0 = blockIdx.y * 128, n0 = blockIdx.x * 128;
    const int sec = n0 >> 12;
    const float* bias = (sec == 0) ? bq : ((sec == 1) ? bk : bv);
    const int tid = threadIdx.x, lane = tid & 63, wid = tid >> 6;
    const int wr = wid >> 1, wc = wid & 1;

    __shared__ bf16_t As[4096];
    __shared__ bf16_t Bs[4096];

    f32x4 acc[4][4];
#pragma unroll
    for (int m = 0; m < 4; ++m)
#pragma unroll
        for (int n = 0; n < 4; ++n) acc[m][n] = (f32x4){0.f, 0.f, 0.f, 0.f};

    const int r0 = wid * 16 + (lane >> 2);
    const int lc = (lane & 3) ^ ((lane >> 2) & 3);
    const long long aOff0 = (long long)(m0 + r0) * 512 + lc * 8;
    const long long aOff1 = (long long)(m0 + r0 + 64) * 512 + lc * 8;
    const long long bOff0 = (long long)(n0 + r0) * 512 + lc * 8;
    const long long bOff1 = (long long)(n0 + r0 + 64) * 512 + lc * 8;
    bf16_t* aDst0 = As + wid * 512;
    bf16_t* aDst1 = As + 2048 + wid * 512;
    bf16_t* bDst0 = Bs + wid * 512;
    bf16_t* bDst1 = Bs + 2048 + wid * 512;

    const int frow = lane & 15, lg = lane >> 4;
    const int pc = lg ^ (frow & 3);

    for (int kt = 0; kt < 512; kt += 32) {
        gload_lds16(A + aOff0 + kt, aDst0);
        gload_lds16(A + aOff1 + kt, aDst1);
        gload_lds16(B + bOff0 + kt, bDst0);
        gload_lds16(B + bOff1 + kt, bDst1);
        __syncthreads();
        bf16x8 af[4], bfv[4];
#pragma unroll
        for (int m = 0; m < 4; ++m)
            af[m] = *reinterpret_cast<const bf16x8*>(As + (wr * 64 + m * 16 + frow) * 32 + pc * 8);
#pragma unroll
        for (int n = 0; n < 4; ++n)
            bfv[n] = *reinterpret_cast<const bf16x8*>(Bs + (wc * 64 + n * 16 + frow) * 32 + pc * 8);
        __builtin_amdgcn_s_setprio(1);
#pragma unroll
        for (int m = 0; m < 4; ++m)
#pragma unroll
            for (int n = 0; n < 4; ++n)
                acc[m][n] = __builtin_amdgcn_mfma_f32_16x16x32_bf16(af[m], bfv[n], acc[m][n], 0, 0, 0);
        __builtin_amdgcn_s_setprio(0);
        __syncthreads();
    }

#pragma unroll
    for (int m = 0; m < 4; ++m) {
        const int gm = m0 + wr * 64 + m * 16 + ((lane >> 4) << 2);
#pragma unroll
        for (int n = 0; n < 4; ++n) {
            const int gn = n0 + wc * 64 + n * 16 + (lane & 15);
            const int gnl = gn & 4095;
            const float bb = bias[gnl];
#pragma unroll
            for (int j = 0; j < 4; ++j) {
                const float v = acc[m][n][j] + bb;
                const int gmj = gm + j;
                if (sec < 2) {
                    qkv[(long long)sec * 33554432 + (long long)gmj * 4096 + gnl] = (bf16_t)v;
                } else {
                    const long long ci =
                        (long long)(((gmj >> 10) * 8 + (gnl >> 9)) * 512 + (gnl & 511)) * 1024 + (gmj & 1023);
                    vtb[ci] = (bf16_t)v;
                }
            }
        }
    }
}

// ---------------- 64x128x32 GEMM via global_load_lds, out = resid + (acc+bias)*alpha
__global__ __launch_bounds__(256) void gemm64_kernel(
    const bf16_t* __restrict__ A, const bf16_t* __restrict__ B,
    const float* __restrict__ bias, float* __restrict__ Cout,
    const float* __restrict__ resid, const float* __restrict__ alpha,
    int M, int N, int K, int lda, int ldb)
{
    const int m0 = blockIdx.y * 64, n0 = blockIdx.x * 128;
    const int tid = threadIdx.x, lane = tid & 63, wid = tid >> 6;
    const int wr = wid >> 1, wc = wid & 1;

    __shared__ bf16_t As[2048];
    __shared__ bf16_t Bs[4096];

    f32x4 acc[2][4];
#pragma unroll
    for (int m = 0; m < 2; ++m)
#pragma unroll
        for (int n = 0; n < 4; ++n) acc[m][n] = (f32x4){0.f, 0.f, 0.f, 0.f};

    const int r0 = wid * 16 + (lane >> 2);
    const int lc = (lane & 3) ^ ((lane >> 2) & 3);
    const long long aOff0 = (long long)(m0 + r0) * lda + lc * 8;
    const long long bOff0 = (long long)(n0 + r0) * ldb + lc * 8;
    const long long bOff1 = (long long)(n0 + r0 + 64) * ldb + lc * 8;
    bf16_t* aDst0 = As + wid * 512;
    bf16_t* bDst0 = Bs + wid * 512;
    bf16_t* bDst1 = Bs + 2048 + wid * 512;

    const int frow = lane & 15, lg = lane >> 4;
    const int pc = lg ^ (frow & 3);

    for (int kt = 0; kt < K; kt += 32) {
        gload_lds16(A + aOff0 + kt, aDst0);
        gload_lds16(B + bOff0 + kt, bDst0);
        gload_lds16(B + bOff1 + kt, bDst1);
        __syncthreads();
        bf16x8 af[2], bfv[4];
#pragma unroll
        for (int m = 0; m < 2; ++m)
            af[m] = *reinterpret_cast<const bf16x8*>(As + (wr * 32 + m * 16 + frow) * 32 + pc * 8);
#pragma unroll
        for (int n = 0; n < 4; ++n)
            bfv[n] = *reinterpret_cast<const bf16x8*>(Bs + (wc * 64 + n * 16 + frow) * 32 + pc * 8);
        __builtin_amdgcn_s_setprio(1);
#pragma unroll
        for (int m = 0; m < 2; ++m)
#pragma unroll
            for (int n = 0; n < 4; ++n)
                acc[m][n] = __builtin_amdgcn_mfma_f32_16x16x32_bf16(af[m], bfv[n], acc[m][n], 0, 0, 0);
        __builtin_amdgcn_s_setprio(0);
        __syncthreads();
    }

#pragma unroll
    for (int m = 0; m < 2; ++m) {
        const int gm = m0 + wr * 32 + m * 16 + ((lane >> 4) << 2);
#pragma unroll
        for (int n = 0; n < 4; ++n) {
            const int gn = n0 + wc * 64 + n * 16 + (lane & 15);
            const float bb = bias[gn];
#pragma unroll
            for (int j = 0; j < 4; ++j) {
                const int gmj = gm + j;
                const long long ci = (long long)gmj * 512 + gn;
                Cout[ci] = resid[ci] + (acc[m][n][j] + bb) * alpha[(gmj >> 10) * 512 + gn];
            }
        }
    }
}

// ---------------- fused flash attention v3: QBLK=128, KVBLK=64, 8 waves
// grid 512: xcd=bid&7, qt=(bid>>3)&7, bhl=bid>>6; Q in regs (per-wave q-tile);
// S role: wave wq=wid owns q-tile (16q), all 64 k-rows. PV role: (we=wid&3, wq2=wid>>2):
// 128e x 64q per wave, acc[8][4]. 2 barriers/iter; delayed running max.
#define FA_LDS 149504
#define SCL 0.04508422132207354f   /* (1/32) * log2(e) */
__global__ __launch_bounds__(512, 2) void flash_kernel(
    bf16_t* __restrict__ qb, const bf16_t* __restrict__ kb, const bf16_t* __restrict__ vtb)
{
    extern __shared__ char smem[];
    bf16_t* Ks = (bf16_t*)smem;                 // [64][512], chunk16 ^ (row&7)
    bf16_t* Vs = (bf16_t*)(smem + 65536);       // [512][64], chunk16 ^ (e&7)
    char* PB = smem + 131072;                   // [128 q][64 k] bf16, chunk16 ^ (q&7)
    float* pmaxB = (float*)(smem + 147456);     // [2][128]
    float* psumB = (float*)(smem + 148480);     // [2][128]

    const int bid = blockIdx.x;
    const int xcd = bid & 7, idx = bid >> 3;
    const int qt = idx & 7, bhl = idx >> 3;
    const int bh = xcd * 8 + bhl;
    const int b = bh >> 3, h = bh & 7;
    const int q0 = qt * 128;
    const int tid = threadIdx.x, lane = tid & 63, wid = tid >> 6;
    const int laneq = lane & 15, lx = lane & 7, lg = lane >> 4;
    const int wq = wid;                       // S role: q-tile
    const int we = wid & 3, wq2 = wid >> 2;   // PV role

    // ---- prologue: stage K(0); Q fragments to registers
#pragma unroll
    for (int r = 0; r < 8; ++r) {
        const int row = r * 8 + wid;
        gload_lds16(kb + ((long long)(b * 1024 + row) * 8 + h) * 512 + ((lane ^ (row & 7)) << 3),
                    Ks + row * 512);
    }
    const int qi = wq * 16 + laneq;
    bf16x8 qfrag[16];
    {
        const bf16_t* qrow = qb + ((long long)(b * 1024 + q0 + qi) * 8 + h) * 512 + lg * 8;
#pragma unroll
        for (int ks = 0; ks < 16; ++ks) qfrag[ks] = *reinterpret_cast<const bf16x8*>(qrow + ks * 32);
    }
    f32x4 acc[8][4];
#pragma unroll
    for (int ef = 0; ef < 8; ++ef)
#pragma unroll
        for (int j = 0; j < 4; ++j) acc[ef][j] = (f32x4){0.f, 0.f, 0.f, 0.f};
    float mS = 0.f;
    float mP[4] = {0.f, 0.f, 0.f, 0.f};
    float l[4] = {0.f, 0.f, 0.f, 0.f};
    __syncthreads();

    for (int t = 0; t < 16; ++t) {
        const int kv0 = t * 64;
        // (a) stage V(t) — hidden under S-phase
#pragma unroll
        for (int r = 0; r < 8; ++r) {
            const int e = r * 64 + wid * 8 + (lane >> 3);
            gload_lds16(vtb + ((long long)bh * 512 + e) * 1024 + kv0 + ((lx ^ (e & 7)) << 3),
                        Vs + (r * 64 + wid * 8) * 64);
        }
        // (b) S-phase: 64 MFMAs (4 k-tiles x 16 k-chunks)
        f32x4 sacc[4];
#pragma unroll
        for (int kt = 0; kt < 4; ++kt) sacc[kt] = (f32x4){0.f, 0.f, 0.f, 0.f};
        const char* KsB = (const char*)Ks;
        __builtin_amdgcn_s_setprio(1);
#pragma unroll
        for (int kt = 0; kt < 4; ++kt) {
            const int rA = kt * 16 + laneq;
#pragma unroll
            for (int ks = 0; ks < 16; ++ks) {
                const int co = ((ks * 4 + lg) ^ lx) << 4;
                bf16x8 a0 = *(const bf16x8*)(KsB + rA * 1024 + co);
                sacc[kt] = __builtin_amdgcn_mfma_f32_16x16x32_bf16(a0, qfrag[ks], sacc[kt], 0, 0, 0);
            }
        }
        __builtin_amdgcn_s_setprio(0);
        // (c) softmax partials (delayed max) + P write
        float f[16];
#pragma unroll
        for (int kt = 0; kt < 4; ++kt)
#pragma unroll
            for (int j = 0; j < 4; ++j) f[kt * 4 + j] = sacc[kt][j] * SCL;
        float mloc = f[0];
#pragma unroll
        for (int j = 1; j < 16; ++j) mloc = fmaxf(mloc, f[j]);
        mloc = fmaxf(mloc, __shfl_xor(mloc, 16));
        mloc = fmaxf(mloc, __shfl_xor(mloc, 32));
        float pe[16]; float sl = 0.f;
#pragma unroll
        for (int j = 0; j < 16; ++j) { pe[j] = exp2f(f[j] - mS); sl += pe[j]; }
        sl += __shfl_xor(sl, 16);
        sl += __shfl_xor(sl, 32);
        if (lane < 16) {
            pmaxB[(t & 1) * 128 + wq * 16 + lane] = mloc;
            psumB[(t & 1) * 128 + wq * 16 + lane] = sl;
        }
        {
            const int hh = (lg & 1) * 8;
#pragma unroll
            for (int kt = 0; kt < 4; ++kt) {
                bf16x4 p;
#pragma unroll
                for (int j = 0; j < 4; ++j) p[j] = (bf16_t)pe[kt * 4 + j];
                const int c = kt * 2 + (lg >> 1);
                *(bf16x4*)(PB + qi * 128 + ((c ^ lx) << 4) + hh) = p;
            }
        }
        __syncthreads();  // (d): V(t), P, stats ready (vmcnt drained)

        // (e) stage K(t+1) — hidden under PV-phase
        if (t < 15) {
#pragma unroll
            for (int r = 0; r < 8; ++r) {
                const int row = r * 8 + wid;
                gload_lds16(kb + ((long long)(b * 1024 + kv0 + 64 + row) * 8 + h) * 512
                                + ((lane ^ (row & 7)) << 3),
                            Ks + row * 512);
            }
        }
        // (f) PV: 64 MFMAs
        const char* VB = (const char*)Vs;
        __builtin_amdgcn_s_setprio(1);
#pragma unroll
        for (int ks2 = 0; ks2 < 2; ++ks2) {
            bf16x8 pf[4];
#pragma unroll
            for (int j = 0; j < 4; ++j) {
                const int q = wq2 * 64 + j * 16 + laneq;
                pf[j] = *(const bf16x8*)(PB + q * 128 + (((ks2 * 4 + lg) ^ lx) << 4));
            }
#pragma unroll
            for (int ef = 0; ef < 8; ++ef) {
                const int re = we * 128 + ef * 16 + laneq;
                bf16x8 av = *(const bf16x8*)(VB + re * 128 + (((ks2 * 4 + lg) ^ lx) << 4));
#pragma unroll
                for (int j = 0; j < 4; ++j)
                    acc[ef][j] = __builtin_amdgcn_mfma_f32_16x16x32_bf16(av, pf[j], acc[ef][j], 0, 0, 0);
            }
        }
        __builtin_amdgcn_s_setprio(0);
        // stats: accumulate in old units, then rescale to new max
        {
            const float* pmax_t = pmaxB + (t & 1) * 128;
            const float* psum_t = psumB + (t & 1) * 128;
            mS = fmaxf(mS, pmax_t[qi]);
            float mn[4]; bool need = false;
#pragma unroll
            for (int j = 0; j < 4; ++j) {
                const int q = wq2 * 64 + j * 16 + laneq;
                l[j] += psum_t[q];
                mn[j] = fmaxf(mP[j], pmax_t[q]);
                need = need || (mn[j] > mP[j]);
            }
            if (__ballot(need)) {
#pragma unroll
                for (int j = 0; j < 4; ++j) {
                    const float rs = exp2f(mP[j] - mn[j]);
                    l[j] *= rs;
#pragma unroll
                    for (int ef = 0; ef < 8; ++ef)
#pragma unroll
                        for (int jj = 0; jj < 4; ++jj) acc[ef][j][jj] *= rs;
                }
            }
#pragma unroll
            for (int j = 0; j < 4; ++j) mP[j] = mn[j];
        }
        __syncthreads();  // (g): K(t+1) ready; P/V reads done
    }

    // ---- epilogue: O = acc / l, store over qb
    float il[4];
#pragma unroll
    for (int j = 0; j < 4; ++j) il[j] = 1.f / l[j];
#pragma unroll
    for (int ef = 0; ef < 8; ++ef) {
        const int e0 = we * 128 + ef * 16 + lg * 4;
#pragma unroll
        for (int j = 0; j < 4; ++j) {
            const int qrow = q0 + wq2 * 64 + j * 16 + laneq;
            bf16x4 o;
#pragma unroll
            for (int jj = 0; jj < 4; ++jj) o[jj] = (bf16_t)(acc[ef][j][jj] * il[j]);
            *(bf16x4*)(qb + ((long long)(b * 1024 + qrow) * 8 + h) * 512 + e0) = o;
        }
    }
}

extern "C" void kernel_launch(void* const* d_in, const int* in_sizes, int n_in,
                              void* d_out, int out_size, void* d_ws, size_t ws_size,
                              hipStream_t stream)
{
    const float* x    = (const float*)d_in[0];
    const float* cond = (const float*)d_in[1];
    const float* g1w  = (const float*)d_in[2];  const float* g1b  = (const float*)d_in[3];
    const float* be1w = (const float*)d_in[4];  const float* be1b = (const float*)d_in[5];
    const float* a1w  = (const float*)d_in[6];  const float* a1b  = (const float*)d_in[7];
    const float* g2w  = (const float*)d_in[8];  const float* g2b  = (const float*)d_in[9];
    const float* be2w = (const float*)d_in[10]; const float* be2b = (const float*)d_in[11];
    const float* a2w  = (const float*)d_in[12]; const float* a2b  = (const float*)d_in[13];
    const float* ln1g = (const float*)d_in[14]; const float* ln1b = (const float*)d_in[15];
    const float* ln2g = (const float*)d_in[16]; const float* ln2b = (const float*)d_in[17];
    const float* wq   = (const float*)d_in[18]; const float* bq   = (const float*)d_in[19];
    const float* wk   = (const float*)d_in[20]; const float* bk   = (const float*)d_in[21];
    const float* wv   = (const float*)d_in[22]; const float* bv   = (const float*)d_in[23];
    const float* lvw  = (const float*)d_in[24]; const float* lvb  = (const float*)d_in[25];
    const float* f1w  = (const float*)d_in[26]; const float* f1b  = (const float*)d_in[27];
    const float* f2w  = (const float*)d_in[28]; const float* f2b  = (const float*)d_in[29];
    (void)in_sizes; (void)n_in; (void)out_size; (void)ws_size;

    // workspace layout (bytes)
    char* w8 = (char*)d_ws;
    float*  mod  = (float*)(w8);                                   //  98304
    bf16_t* wqT  = (bf16_t*)(w8 + 98304);                          // 4096x512 bf16 (wq/wk/wv contiguous)
    bf16_t* wkT  = (bf16_t*)(w8 + 98304 + 4194304);
    bf16_t* wvT  = (bf16_t*)(w8 + 98304 + 2 * 4194304);
    bf16_t* lvwT = (bf16_t*)(w8 + 98304 + 3 * 4194304);            // 512x4096
    bf16_t* f1wT = (bf16_t*)(w8 + 98304 + 4 * 4194304);            // 2048x512
    bf16_t* f2wT = (bf16_t*)(w8 + 98304 + 4 * 4194304 + 2097152);  // 512x2048
    bf16_t* ybf  = (bf16_t*)(w8 + 98304 + 4 * 4194304 + 2 * 2097152);           // 8192x512
    bf16_t* qb   = (bf16_t*)(w8 + 98304 + 4 * 4194304 + 2 * 2097152 + 8388608); // (b,s,h,e); O in place
    bf16_t* kb   = qb + 33554432;    // (b,s,h,e)  (contiguous after qb)
    bf16_t* vtb  = kb + 33554432;    // V transposed: (b,h,e,s)

    (void)hipFuncSetAttribute((const void*)flash_kernel,
                              hipFuncAttributeMaxDynamicSharedMemorySize, FA_LDS);

    const dim3 blk(256);
    // weights -> bf16 transposed
    wtrans_kernel<<<dim3(128, 16), blk, 0, stream>>>(wq, wqT, 512, 4096);
    wtrans_kernel<<<dim3(128, 16), blk, 0, stream>>>(wk, wkT, 512, 4096);
    wtrans_kernel<<<dim3(128, 16), blk, 0, stream>>>(wv, wvT, 512, 4096);
    wtrans_kernel<<<dim3(16, 128), blk, 0, stream>>>(lvw, lvwT, 4096, 512);
    wtrans_kernel<<<dim3(64, 16), blk, 0, stream>>>(f1w, f1wT, 512, 2048);
    wtrans_kernel<<<dim3(16, 64), blk, 0, stream>>>(f2w, f2wT, 2048, 512);
    // modulation signals
    modsig_kernel<<<48, blk, 0, stream>>>(cond, g1w, be1w, a1w, g2w, be2w, a2w,
                                          g1b, be1b, a1b, g2b, be2b, a2b, mod);
    // LN1 + modulate -> y (bf16)
    ln_mod_kernel<<<8192, 128, 0, stream>>>(x, ln1g, ln1b, mod, mod + 4096, ybf);
    // fused QKV projection (V stored transposed)
    gemmqkv_kernel<<<dim3(96, 64), blk, 0, stream>>>(ybf, wqT, bq, bk, bv, qb, vtb);
    // fused flash attention: O overwrites qb
    flash_kernel<<<512, 512, FA_LDS, stream>>>(qb, kb, vtb);
    // y2 = x + (O @ lvw + lvb) * alpha1 -> d_out (fp32)
    gemm64_kernel<<<dim3(4, 128), blk, 0, stream>>>(qb, lvwT, lvb, (float*)d_out, x, mod + 8192,
        8192, 512, 4096, 4096, 4096);
    // LN2 + modulate -> z (bf16)
    ln_mod_kernel<<<8192, 128, 0, stream>>>((const float*)d_out, ln2g, ln2b,
                                            mod + 12288, mod + 16384, ybf);
    // FFN
    gemm128_kernel<1><<<dim3(16, 64), blk, 0, stream>>>(ybf, f1wT, f1b, qb,
        8192, 2048, 512, 512, 512, 2048);
    gemm64_kernel<<<dim3(4, 128), blk, 0, stream>>>(qb, f2wT, f2b, (float*)d_out,
        (const float*)d_out, mod + 20480,
        8192, 512, 2048, 2048, 2048);
}

// Round 6
// 852.011 us; speedup vs baseline: 1.0627x; 1.0627x over previous
//
#include <hip/hip_runtime.h>
#include <hip/hip_bf16.h>

typedef __bf16 bf16_t;
typedef bf16_t bf16x8 __attribute__((ext_vector_type(8)));
typedef bf16_t bf16x4 __attribute__((ext_vector_type(4)));
typedef float f32x4 __attribute__((ext_vector_type(4)));

typedef const __attribute__((address_space(1))) void GV;
typedef __attribute__((address_space(3))) void LV;

__device__ __forceinline__ void gload_lds16(const bf16_t* gsrc, bf16_t* ldst) {
    __builtin_amdgcn_global_load_lds((GV*)gsrc, (LV*)ldst, 16, 0, 0);
}

// ---------------- weight transpose+convert: in fp32 (K x N) -> out bf16 (N x K)
__global__ __launch_bounds__(256) void wtrans_kernel(const float* __restrict__ in,
                                                     bf16_t* __restrict__ out, int K, int N)
{
    __shared__ float tile[32][33];
    const int n0 = blockIdx.x * 32, k0 = blockIdx.y * 32;
    const int tx = threadIdx.x & 31, ty = threadIdx.x >> 5;  // 32 x 8
#pragma unroll
    for (int i = 0; i < 32; i += 8)
        tile[ty + i][tx] = in[(long long)(k0 + ty + i) * N + n0 + tx];
    __syncthreads();
#pragma unroll
    for (int i = 0; i < 32; i += 8)
        out[(long long)(n0 + ty + i) * K + k0 + tx] = (bf16_t)tile[tx][ty + i];
}

// ---------------- 6 modulation linears on cond: out[(sig*8+b)*512 + n]
__global__ __launch_bounds__(256) void modsig_kernel(
    const float* __restrict__ cond,
    const float* __restrict__ w0, const float* __restrict__ w1, const float* __restrict__ w2,
    const float* __restrict__ w3, const float* __restrict__ w4, const float* __restrict__ w5,
    const float* __restrict__ c0, const float* __restrict__ c1, const float* __restrict__ c2,
    const float* __restrict__ c3, const float* __restrict__ c4, const float* __restrict__ c5,
    float* __restrict__ out)
{
    __shared__ float cs[512];
    const int sig = blockIdx.x >> 3, b = blockIdx.x & 7;
    const float* w; const float* bi;
    switch (sig) {
        case 0: w = w0; bi = c0; break;
        case 1: w = w1; bi = c1; break;
        case 2: w = w2; bi = c2; break;
        case 3: w = w3; bi = c3; break;
        case 4: w = w4; bi = c4; break;
        default: w = w5; bi = c5; break;
    }
    for (int i = threadIdx.x; i < 512; i += 256) cs[i] = cond[b * 512 + i];
    __syncthreads();
    for (int n = threadIdx.x; n < 512; n += 256) {
        float s = bi[n];
        for (int i = 0; i < 512; ++i) s = fmaf(cs[i], w[(long long)i * 512 + n], s);
        out[(long long)(sig * 8 + b) * 512 + n] = s;
    }
}

// ---------------- fused LayerNorm + AdaLN modulate, fp32 -> bf16
__global__ __launch_bounds__(128) void ln_mod_kernel(
    const float* __restrict__ x, const float* __restrict__ g, const float* __restrict__ be,
    const float* __restrict__ gamma, const float* __restrict__ beta, bf16_t* __restrict__ out)
{
    const int row = blockIdx.x;
    const int b = row >> 10;
    const int t = threadIdx.x;
    const float4 v = reinterpret_cast<const float4*>(x + (long long)row * 512)[t];
    float s = v.x + v.y + v.z + v.w;
    float ss = v.x * v.x + v.y * v.y + v.z * v.z + v.w * v.w;
    for (int o = 32; o; o >>= 1) { s += __shfl_xor(s, o); ss += __shfl_xor(ss, o); }
    __shared__ float red[4];
    if ((t & 63) == 0) { red[t >> 6] = s; red[2 + (t >> 6)] = ss; }
    __syncthreads();
    s = red[0] + red[1]; ss = red[2] + red[3];
    const float mu = s * (1.f / 512.f);
    const float rstd = rsqrtf(ss * (1.f / 512.f) - mu * mu + 1e-5f);
    const float4 gv = reinterpret_cast<const float4*>(g)[t];
    const float4 bv = reinterpret_cast<const float4*>(be)[t];
    const float4 ga = reinterpret_cast<const float4*>(gamma + b * 512)[t];
    const float4 bb = reinterpret_cast<const float4*>(beta + b * 512)[t];
    bf16x4 ov;
    ov[0] = (bf16_t)(((v.x - mu) * rstd * gv.x + bv.x) * (1.f + ga.x) + bb.x);
    ov[1] = (bf16_t)(((v.y - mu) * rstd * gv.y + bv.y) * (1.f + ga.y) + bb.y);
    ov[2] = (bf16_t)(((v.z - mu) * rstd * gv.z + bv.z) * (1.f + ga.z) + bb.z);
    ov[3] = (bf16_t)(((v.w - mu) * rstd * gv.w + bv.w) * (1.f + ga.w) + bb.w);
    reinterpret_cast<bf16x4*>(out + (long long)row * 512)[t] = ov;
}

// ---------------- 128x128x32 bf16 MFMA GEMM via global_load_lds, C = A * B^T
template <int EPI>
__global__ __launch_bounds__(256) void gemm128_kernel(
    const bf16_t* __restrict__ A, const bf16_t* __restrict__ B,
    const float* __restrict__ bias, void* Cout,
    int M, int N, int K, int lda, int ldb, int ldc)
{
    const int m0 = blockIdx.y * 128, n0 = blockIdx.x * 128;
    const int tid = threadIdx.x, lane = tid & 63, wid = tid >> 6;
    const int wr = wid >> 1, wc = wid & 1;

    __shared__ bf16_t As[4096];
    __shared__ bf16_t Bs[4096];

    f32x4 acc[4][4];
#pragma unroll
    for (int m = 0; m < 4; ++m)
#pragma unroll
        for (int n = 0; n < 4; ++n) acc[m][n] = (f32x4){0.f, 0.f, 0.f, 0.f};

    const int r0 = wid * 16 + (lane >> 2);
    const int lc = (lane & 3) ^ ((lane >> 2) & 3);
    const long long aOff0 = (long long)(m0 + r0) * lda + lc * 8;
    const long long aOff1 = (long long)(m0 + r0 + 64) * lda + lc * 8;
    const long long bOff0 = (long long)(n0 + r0) * ldb + lc * 8;
    const long long bOff1 = (long long)(n0 + r0 + 64) * ldb + lc * 8;
    bf16_t* aDst0 = As + wid * 512;
    bf16_t* aDst1 = As + 2048 + wid * 512;
    bf16_t* bDst0 = Bs + wid * 512;
    bf16_t* bDst1 = Bs + 2048 + wid * 512;

    const int frow = lane & 15, lg = lane >> 4;
    const int pc = lg ^ (frow & 3);

    for (int kt = 0; kt < K; kt += 32) {
        gload_lds16(A + aOff0 + kt, aDst0);
        gload_lds16(A + aOff1 + kt, aDst1);
        gload_lds16(B + bOff0 + kt, bDst0);
        gload_lds16(B + bOff1 + kt, bDst1);
        __syncthreads();
        bf16x8 af[4], bfv[4];
#pragma unroll
        for (int m = 0; m < 4; ++m)
            af[m] = *reinterpret_cast<const bf16x8*>(As + (wr * 64 + m * 16 + frow) * 32 + pc * 8);
#pragma unroll
        for (int n = 0; n < 4; ++n)
            bfv[n] = *reinterpret_cast<const bf16x8*>(Bs + (wc * 64 + n * 16 + frow) * 32 + pc * 8);
        __builtin_amdgcn_s_setprio(1);
#pragma unroll
        for (int m = 0; m < 4; ++m)
#pragma unroll
            for (int n = 0; n < 4; ++n)
                acc[m][n] = __builtin_amdgcn_mfma_f32_16x16x32_bf16(af[m], bfv[n], acc[m][n], 0, 0, 0);
        __builtin_amdgcn_s_setprio(0);
        __syncthreads();
    }

#pragma unroll
    for (int m = 0; m < 4; ++m) {
        const int gm = m0 + wr * 64 + m * 16 + ((lane >> 4) << 2);
#pragma unroll
        for (int n = 0; n < 4; ++n) {
            const int gn = n0 + wc * 64 + n * 16 + (lane & 15);
            const float bb = bias ? bias[gn] : 0.f;
#pragma unroll
            for (int j = 0; j < 4; ++j) {
                const float v = acc[m][n][j] + bb;
                const int gmj = gm + j;
                if (EPI == 0) {
                    ((bf16_t*)Cout)[(long long)gmj * ldc + gn] = (bf16_t)v;
                } else {
                    ((bf16_t*)Cout)[(long long)gmj * ldc + gn] = (bf16_t)fmaxf(v, 0.f);
                }
            }
        }
    }
}

// ---------------- fused QKV GEMM: B = [wqT;wkT;wvT] (12288 x 512 contiguous)
// n-section 0 -> qb, 1 -> kb, 2 -> vfr (V in MFMA-A-fragment order)
// vfr index: [bh][t=s>>6][ks2=(s>>5)&1][et=e>>4][lane=( (s>>3)&3 )*16 + (e&15)][j=s&7]
__global__ __launch_bounds__(256) void gemmqkv_kernel(
    const bf16_t* __restrict__ A, const bf16_t* __restrict__ B,
    const float* __restrict__ bq, const float* __restrict__ bk, const float* __restrict__ bv,
    bf16_t* __restrict__ qkv, bf16_t* __restrict__ vfr)
{
    const int m0 = blockIdx.y * 128, n0 = blockIdx.x * 128;
    const int sec = n0 >> 12;
    const float* bias = (sec == 0) ? bq : ((sec == 1) ? bk : bv);
    const int tid = threadIdx.x, lane = tid & 63, wid = tid >> 6;
    const int wr = wid >> 1, wc = wid & 1;

    __shared__ bf16_t As[4096];
    __shared__ bf16_t Bs[4096];

    f32x4 acc[4][4];
#pragma unroll
    for (int m = 0; m < 4; ++m)
#pragma unroll
        for (int n = 0; n < 4; ++n) acc[m][n] = (f32x4){0.f, 0.f, 0.f, 0.f};

    const int r0 = wid * 16 + (lane >> 2);
    const int lc = (lane & 3) ^ ((lane >> 2) & 3);
    const long long aOff0 = (long long)(m0 + r0) * 512 + lc * 8;
    const long long aOff1 = (long long)(m0 + r0 + 64) * 512 + lc * 8;
    const long long bOff0 = (long long)(n0 + r0) * 512 + lc * 8;
    const long long bOff1 = (long long)(n0 + r0 + 64) * 512 + lc * 8;
    bf16_t* aDst0 = As + wid * 512;
    bf16_t* aDst1 = As + 2048 + wid * 512;
    bf16_t* bDst0 = Bs + wid * 512;
    bf16_t* bDst1 = Bs + 2048 + wid * 512;

    const int frow = lane & 15, lg = lane >> 4;
    const int pc = lg ^ (frow & 3);

    for (int kt = 0; kt < 512; kt += 32) {
        gload_lds16(A + aOff0 + kt, aDst0);
        gload_lds16(A + aOff1 + kt, aDst1);
        gload_lds16(B + bOff0 + kt, bDst0);
        gload_lds16(B + bOff1 + kt, bDst1);
        __syncthreads();
        bf16x8 af[4], bfv[4];
#pragma unroll
        for (int m = 0; m < 4; ++m)
            af[m] = *reinterpret_cast<const bf16x8*>(As + (wr * 64 + m * 16 + frow) * 32 + pc * 8);
#pragma unroll
        for (int n = 0; n < 4; ++n)
            bfv[n] = *reinterpret_cast<const bf16x8*>(Bs + (wc * 64 + n * 16 + frow) * 32 + pc * 8);
        __builtin_amdgcn_s_setprio(1);
#pragma unroll
        for (int m = 0; m < 4; ++m)
#pragma unroll
            for (int n = 0; n < 4; ++n)
                acc[m][n] = __builtin_amdgcn_mfma_f32_16x16x32_bf16(af[m], bfv[n], acc[m][n], 0, 0, 0);
        __builtin_amdgcn_s_setprio(0);
        __syncthreads();
    }

#pragma unroll
    for (int m = 0; m < 4; ++m) {
        const int gm = m0 + wr * 64 + m * 16 + ((lane >> 4) << 2);
#pragma unroll
        for (int n = 0; n < 4; ++n) {
            const int gn = n0 + wc * 64 + n * 16 + (lane & 15);
            const int gnl = gn & 4095;
            const float bb = bias[gnl];
            if (sec < 2) {
#pragma unroll
                for (int j = 0; j < 4; ++j) {
                    const int gmj = gm + j;
                    qkv[(long long)sec * 33554432 + (long long)gmj * 4096 + gnl] =
                        (bf16_t)(acc[m][n][j] + bb);
                }
            } else {
                // V fragment layout; the 4 j's are s..s+3 within one 8-elem granule
                const int s = gm & 1023, bb2 = gm >> 10;
                const int hh = gnl >> 9, e = gnl & 511;
                const int bh = bb2 * 8 + hh;
                const long long ci = ((long long)bh << 19) + ((s >> 6) * 32768)
                                   + (((s >> 5) & 1) * 16384) + ((e >> 4) * 512)
                                   + (((s >> 3) & 3) * 128) + ((e & 15) * 8) + (s & 7);
                bf16x4 ov;
#pragma unroll
                for (int j = 0; j < 4; ++j) ov[j] = (bf16_t)(acc[m][n][j] + bb);
                *reinterpret_cast<bf16x4*>(vfr + ci) = ov;
            }
        }
    }
}

// ---------------- 64x128x32 GEMM via global_load_lds, out = resid + (acc+bias)*alpha
__global__ __launch_bounds__(256) void gemm64_kernel(
    const bf16_t* __restrict__ A, const bf16_t* __restrict__ B,
    const float* __restrict__ bias, float* __restrict__ Cout,
    const float* __restrict__ resid, const float* __restrict__ alpha,
    int M, int N, int K, int lda, int ldb)
{
    const int m0 = blockIdx.y * 64, n0 = blockIdx.x * 128;
    const int tid = threadIdx.x, lane = tid & 63, wid = tid >> 6;
    const int wr = wid >> 1, wc = wid & 1;

    __shared__ bf16_t As[2048];
    __shared__ bf16_t Bs[4096];

    f32x4 acc[2][4];
#pragma unroll
    for (int m = 0; m < 2; ++m)
#pragma unroll
        for (int n = 0; n < 4; ++n) acc[m][n] = (f32x4){0.f, 0.f, 0.f, 0.f};

    const int r0 = wid * 16 + (lane >> 2);
    const int lc = (lane & 3) ^ ((lane >> 2) & 3);
    const long long aOff0 = (long long)(m0 + r0) * lda + lc * 8;
    const long long bOff0 = (long long)(n0 + r0) * ldb + lc * 8;
    const long long bOff1 = (long long)(n0 + r0 + 64) * ldb + lc * 8;
    bf16_t* aDst0 = As + wid * 512;
    bf16_t* bDst0 = Bs + wid * 512;
    bf16_t* bDst1 = Bs + 2048 + wid * 512;

    const int frow = lane & 15, lg = lane >> 4;
    const int pc = lg ^ (frow & 3);

    for (int kt = 0; kt < K; kt += 32) {
        gload_lds16(A + aOff0 + kt, aDst0);
        gload_lds16(B + bOff0 + kt, bDst0);
        gload_lds16(B + bOff1 + kt, bDst1);
        __syncthreads();
        bf16x8 af[2], bfv[4];
#pragma unroll
        for (int m = 0; m < 2; ++m)
            af[m] = *reinterpret_cast<const bf16x8*>(As + (wr * 32 + m * 16 + frow) * 32 + pc * 8);
#pragma unroll
        for (int n = 0; n < 4; ++n)
            bfv[n] = *reinterpret_cast<const bf16x8*>(Bs + (wc * 64 + n * 16 + frow) * 32 + pc * 8);
        __builtin_amdgcn_s_setprio(1);
#pragma unroll
        for (int m = 0; m < 2; ++m)
#pragma unroll
            for (int n = 0; n < 4; ++n)
                acc[m][n] = __builtin_amdgcn_mfma_f32_16x16x32_bf16(af[m], bfv[n], acc[m][n], 0, 0, 0);
        __builtin_amdgcn_s_setprio(0);
        __syncthreads();
    }

#pragma unroll
    for (int m = 0; m < 2; ++m) {
        const int gm = m0 + wr * 32 + m * 16 + ((lane >> 4) << 2);
#pragma unroll
        for (int n = 0; n < 4; ++n) {
            const int gn = n0 + wc * 64 + n * 16 + (lane & 15);
            const float bb = bias[gn];
#pragma unroll
            for (int j = 0; j < 4; ++j) {
                const int gmj = gm + j;
                const long long ci = (long long)gmj * 512 + gn;
                Cout[ci] = resid[ci] + (acc[m][n][j] + bb) * alpha[(gmj >> 10) * 512 + gn];
            }
        }
    }
}

// ---------------- fused flash attention v4 = v2 (round-4) + V-from-global fragments
// QBLK=64, KVBLK=64, 8 waves. K staged in LDS (swizzled); V read as coalesced
// MFMA-A fragments from vfr directly into registers (no V LDS buffer).
#define FA_LDS 75776
#define SCL 0.04508422132207354f   /* (1/32) * log2(e) */
__global__ __launch_bounds__(512, 2) void flash_kernel(
    bf16_t* __restrict__ qb, const bf16_t* __restrict__ kb, const bf16_t* __restrict__ vfr)
{
    extern __shared__ char smem[];
    bf16_t* Ks = (bf16_t*)smem;                 // [64][512], chunk16 ^ (row&7)
    char* PB = smem + 65536;                    // [64 q][64 k] bf16, 8B gran ^ ((q&7)<<1)
    float* pmaxB = (float*)(smem + 73728);      // [2][2][64]
    float* psumB = (float*)(smem + 74752);      // [2][2][64]

    const int bid = blockIdx.x;
    const int xcd = bid & 7, idx = bid >> 3;
    const int qt = idx & 15, bhl = idx >> 4;
    const int bh = xcd * 8 + bhl;
    const int b = bh >> 3, h = bh & 7;
    const int q0 = qt * 64;
    const int tid = threadIdx.x, lane = tid & 63, wid = tid >> 6;
    const int laneq = lane & 15, lg = lane >> 4;
    const int wk = wid >> 2, wq = wid & 3;      // S role
    const int we = wid & 3, wq2 = wid >> 2;     // PV role

    // ---- prologue: stage K(0); load Q frags to registers
#pragma unroll
    for (int r = 0; r < 8; ++r) {
        const int row = r * 8 + wid;
        gload_lds16(kb + ((long long)(b * 1024 + row) * 8 + h) * 512 + ((lane ^ (row & 7)) << 3),
                    Ks + row * 512);
    }
    const int qi = wq * 16 + laneq;
    bf16x8 qfrag[16];
    {
        const bf16_t* qrow = qb + ((long long)(b * 1024 + q0 + qi) * 8 + h) * 512 + lg * 8;
#pragma unroll
        for (int ks = 0; ks < 16; ++ks) qfrag[ks] = *reinterpret_cast<const bf16x8*>(qrow + ks * 32);
    }
    f32x4 accA[8], accB[8];
#pragma unroll
    for (int e = 0; e < 8; ++e) { accA[e] = (f32x4){0.f,0.f,0.f,0.f}; accB[e] = (f32x4){0.f,0.f,0.f,0.f}; }
    float mS = 0.f, mPA = 0.f, mPB = 0.f, lA = 0.f, lB = 0.f;
    const int rA0 = wk * 32 + laneq, rA1 = rA0 + 16;
    const int qA = wq2 * 32 + laneq, qB = qA + 16;
    const int qx = (qi & 7) << 1;
    const int qxA = (qA & 7) << 1, qxB = (qB & 7) << 1;
    // per-(bh) V-fragment base; this wave's e-quarter, this lane's 16B
    const bf16_t* vfrW = vfr + ((long long)bh << 19) + (we * 8) * 512 + lane * 8;
    __syncthreads();

    for (int t = 0; t < 16; ++t) {
        // (a) issue V fragment loads for ks2=0 — hidden under S-phase
        const bf16_t* vfrT = vfrW + t * 32768;
        bf16x8 av0[8], av1[8];
#pragma unroll
        for (int ef = 0; ef < 8; ++ef)
            av0[ef] = *reinterpret_cast<const bf16x8*>(vfrT + ef * 512);
        // (b) S-phase: S^T = K · Q^T
        f32x4 s0 = (f32x4){0.f,0.f,0.f,0.f}, s1 = (f32x4){0.f,0.f,0.f,0.f};
        const char* KsB = (const char*)Ks;
        __builtin_amdgcn_s_setprio(1);
#pragma unroll
        for (int ks = 0; ks < 16; ++ks) {
            const int co = ((ks * 4 + lg) ^ (lane & 7)) << 4;
            bf16x8 a0 = *(const bf16x8*)(KsB + rA0 * 1024 + co);
            bf16x8 a1 = *(const bf16x8*)(KsB + rA1 * 1024 + co);
            s0 = __builtin_amdgcn_mfma_f32_16x16x32_bf16(a0, qfrag[ks], s0, 0, 0, 0);
            s1 = __builtin_amdgcn_mfma_f32_16x16x32_bf16(a1, qfrag[ks], s1, 0, 0, 0);
        }
        __builtin_amdgcn_s_setprio(0);
        // (c) delayed-max softmax partials + P write
        float f[8];
#pragma unroll
        for (int j = 0; j < 4; ++j) { f[j] = s0[j] * SCL; f[4 + j] = s1[j] * SCL; }
        float mloc = f[0];
#pragma unroll
        for (int j = 1; j < 8; ++j) mloc = fmaxf(mloc, f[j]);
        mloc = fmaxf(mloc, __shfl_xor(mloc, 16));
        mloc = fmaxf(mloc, __shfl_xor(mloc, 32));
        float pe[8]; float sl = 0.f;
#pragma unroll
        for (int j = 0; j < 8; ++j) { pe[j] = exp2f(f[j] - mS); sl += pe[j]; }
        sl += __shfl_xor(sl, 16);
        sl += __shfl_xor(sl, 32);
        if (lane < 16) {
            pmaxB[(t & 1) * 128 + wk * 64 + wq * 16 + lane] = mloc;
            psumB[(t & 1) * 128 + wk * 64 + wq * 16 + lane] = sl;
        }
        {
            bf16x4 p0, p1;
#pragma unroll
            for (int j = 0; j < 4; ++j) { p0[j] = (bf16_t)pe[j]; p1[j] = (bf16_t)pe[4 + j]; }
            const int kc0 = wk * 8 + lg, kc1 = kc0 + 4;
            *(bf16x4*)(PB + qi * 128 + ((kc0 ^ qx) << 3)) = p0;
            *(bf16x4*)(PB + qi * 128 + ((kc1 ^ qx) << 3)) = p1;
        }
        __syncthreads();  // (d): P + stats ready (vmcnt drained; av0 landed long ago)

        // (e1) issue V fragment loads for ks2=1
#pragma unroll
        for (int ef = 0; ef < 8; ++ef)
            av1[ef] = *reinterpret_cast<const bf16x8*>(vfrT + 16384 + ef * 512);
        // (e2) stage K(t+1) — hidden under PV-phase
        if (t < 15) {
#pragma unroll
            for (int r = 0; r < 8; ++r) {
                const int row = r * 8 + wid;
                gload_lds16(kb + ((long long)(b * 1024 + t * 64 + 64 + row) * 8 + h) * 512
                                + ((lane ^ (row & 7)) << 3),
                            Ks + row * 512);
            }
        }
        // (f) PV: ks2=0 with av0, ks2=1 with av1
        __builtin_amdgcn_s_setprio(1);
        {
            const int kcp0 = lg * 2;
            bf16x8 pA = *(const bf16x8*)(PB + qA * 128 + ((kcp0 ^ qxA) << 3));
            bf16x8 pBv = *(const bf16x8*)(PB + qB * 128 + ((kcp0 ^ qxB) << 3));
#pragma unroll
            for (int ef = 0; ef < 8; ++ef) {
                accA[ef] = __builtin_amdgcn_mfma_f32_16x16x32_bf16(av0[ef], pA, accA[ef], 0, 0, 0);
                accB[ef] = __builtin_amdgcn_mfma_f32_16x16x32_bf16(av0[ef], pBv, accB[ef], 0, 0, 0);
            }
        }
        {
            const int kcp1 = 8 + lg * 2;
            bf16x8 pA = *(const bf16x8*)(PB + qA * 128 + ((kcp1 ^ qxA) << 3));
            bf16x8 pBv = *(const bf16x8*)(PB + qB * 128 + ((kcp1 ^ qxB) << 3));
#pragma unroll
            for (int ef = 0; ef < 8; ++ef) {
                accA[ef] = __builtin_amdgcn_mfma_f32_16x16x32_bf16(av1[ef], pA, accA[ef], 0, 0, 0);
                accB[ef] = __builtin_amdgcn_mfma_f32_16x16x32_bf16(av1[ef], pBv, accB[ef], 0, 0, 0);
            }
        }
        __builtin_amdgcn_s_setprio(0);
        // stats: accumulate in old units, then rescale to new max
        {
            const float* pmax_t = pmaxB + (t & 1) * 128;
            const float* psum_t = psumB + (t & 1) * 128;
            mS = fmaxf(mS, fmaxf(pmax_t[qi], pmax_t[64 + qi]));
            lA += psum_t[qA] + psum_t[64 + qA];
            lB += psum_t[qB] + psum_t[64 + qB];
            const float mnA = fmaxf(mPA, fmaxf(pmax_t[qA], pmax_t[64 + qA]));
            const float mnB = fmaxf(mPB, fmaxf(pmax_t[qB], pmax_t[64 + qB]));
            if (__ballot((mnA > mPA) || (mnB > mPB))) {
                const float rA = exp2f(mPA - mnA), rB = exp2f(mPB - mnB);
                lA *= rA; lB *= rB;
#pragma unroll
                for (int e = 0; e < 8; ++e) {
#pragma unroll
                    for (int j = 0; j < 4; ++j) { accA[e][j] *= rA; accB[e][j] *= rB; }
                }
            }
            mPA = mnA; mPB = mnB;
        }
        __syncthreads();  // (g): K(t+1) ready; P reads done
    }

    // ---- epilogue: O = acc / l, store over qb
    const float iA = 1.f / lA, iB = 1.f / lB;
#pragma unroll
    for (int ef = 0; ef < 8; ++ef) {
        const int e0 = we * 128 + ef * 16 + lg * 4;
        bf16x4 oA, oB;
#pragma unroll
        for (int j = 0; j < 4; ++j) { oA[j] = (bf16_t)(accA[ef][j] * iA); oB[j] = (bf16_t)(accB[ef][j] * iB); }
        *(bf16x4*)(qb + ((long long)(b * 1024 + q0 + qA) * 8 + h) * 512 + e0) = oA;
        *(bf16x4*)(qb + ((long long)(b * 1024 + q0 + qB) * 8 + h) * 512 + e0) = oB;
    }
}

extern "C" void kernel_launch(void* const* d_in, const int* in_sizes, int n_in,
                              void* d_out, int out_size, void* d_ws, size_t ws_size,
                              hipStream_t stream)
{
    const float* x    = (const float*)d_in[0];
    const float* cond = (const float*)d_in[1];
    const float* g1w  = (const float*)d_in[2];  const float* g1b  = (const float*)d_in[3];
    const float* be1w = (const float*)d_in[4];  const float* be1b = (const float*)d_in[5];
    const float* a1w  = (const float*)d_in[6];  const float* a1b  = (const float*)d_in[7];
    const float* g2w  = (const float*)d_in[8];  const float* g2b  = (const float*)d_in[9];
    const float* be2w = (const float*)d_in[10]; const float* be2b = (const float*)d_in[11];
    const float* a2w  = (const float*)d_in[12]; const float* a2b  = (const float*)d_in[13];
    const float* ln1g = (const float*)d_in[14]; const float* ln1b = (const float*)d_in[15];
    const float* ln2g = (const float*)d_in[16]; const float* ln2b = (const float*)d_in[17];
    const float* wq   = (const float*)d_in[18]; const float* bq   = (const float*)d_in[19];
    const float* wk   = (const float*)d_in[20]; const float* bk   = (const float*)d_in[21];
    const float* wv   = (const float*)d_in[22]; const float* bv   = (const float*)d_in[23];
    const float* lvw  = (const float*)d_in[24]; const float* lvb  = (const float*)d_in[25];
    const float* f1w  = (const float*)d_in[26]; const float* f1b  = (const float*)d_in[27];
    const float* f2w  = (const float*)d_in[28]; const float* f2b  = (const float*)d_in[29];
    (void)in_sizes; (void)n_in; (void)out_size; (void)ws_size;

    // workspace layout (bytes)
    char* w8 = (char*)d_ws;
    float*  mod  = (float*)(w8);                                   //  98304
    bf16_t* wqT  = (bf16_t*)(w8 + 98304);                          // 4096x512 bf16 (wq/wk/wv contiguous)
    bf16_t* lvwT = (bf16_t*)(w8 + 98304 + 3 * 4194304);            // 512x4096
    bf16_t* f1wT = (bf16_t*)(w8 + 98304 + 4 * 4194304);            // 2048x512
    bf16_t* f2wT = (bf16_t*)(w8 + 98304 + 4 * 4194304 + 2097152);  // 512x2048
    bf16_t* ybf  = (bf16_t*)(w8 + 98304 + 4 * 4194304 + 2 * 2097152);           // 8192x512
    bf16_t* qb   = (bf16_t*)(w8 + 98304 + 4 * 4194304 + 2 * 2097152 + 8388608); // (b,s,h,e); O in place
    bf16_t* kb   = qb + 33554432;    // (b,s,h,e)
    bf16_t* vfr  = kb + 33554432;    // V in MFMA fragment order

    (void)hipFuncSetAttribute((const void*)flash_kernel,
                              hipFuncAttributeMaxDynamicSharedMemorySize, FA_LDS);

    const dim3 blk(256);
    // weights -> bf16 transposed
    wtrans_kernel<<<dim3(128, 16), blk, 0, stream>>>(wq, wqT, 512, 4096);
    wtrans_kernel<<<dim3(128, 16), blk, 0, stream>>>(wk, wqT + 2097152, 512, 4096);
    wtrans_kernel<<<dim3(128, 16), blk, 0, stream>>>(wv, wqT + 2 * 2097152, 512, 4096);
    wtrans_kernel<<<dim3(16, 128), blk, 0, stream>>>(lvw, lvwT, 4096, 512);
    wtrans_kernel<<<dim3(64, 16), blk, 0, stream>>>(f1w, f1wT, 512, 2048);
    wtrans_kernel<<<dim3(16, 64), blk, 0, stream>>>(f2w, f2wT, 2048, 512);
    // modulation signals
    modsig_kernel<<<48, blk, 0, stream>>>(cond, g1w, be1w, a1w, g2w, be2w, a2w,
                                          g1b, be1b, a1b, g2b, be2b, a2b, mod);
    // LN1 + modulate -> y (bf16)
    ln_mod_kernel<<<8192, 128, 0, stream>>>(x, ln1g, ln1b, mod, mod + 4096, ybf);
    // fused QKV projection (V stored in fragment order)
    gemmqkv_kernel<<<dim3(96, 64), blk, 0, stream>>>(ybf, wqT, bq, bk, bv, qb, vfr);
    // fused flash attention: O overwrites qb
    flash_kernel<<<1024, 512, FA_LDS, stream>>>(qb, kb, vfr);
    // y2 = x + (O @ lvw + lvb) * alpha1 -> d_out (fp32)
    gemm64_kernel<<<dim3(4, 128), blk, 0, stream>>>(qb, lvwT, lvb, (float*)d_out, x, mod + 8192,
        8192, 512, 4096, 4096, 4096);
    // LN2 + modulate -> z (bf16)
    ln_mod_kernel<<<8192, 128, 0, stream>>>((const float*)d_out, ln2g, ln2b,
                                            mod + 12288, mod + 16384, ybf);
    // FFN
    gemm128_kernel<1><<<dim3(16, 64), blk, 0, stream>>>(ybf, f1wT, f1b, qb,
        8192, 2048, 512, 512, 512, 2048);
    gemm64_kernel<<<dim3(4, 128), blk, 0, stream>>>(qb, f2wT, f2b, (float*)d_out,
        (const float*)d_out, mod + 20480,
        8192, 512, 2048, 2048, 2048);
}

// Round 7
// 748.024 us; speedup vs baseline: 1.2104x; 1.1390x over previous
//
#include <hip/hip_runtime.h>
#include <hip/hip_bf16.h>

typedef __bf16 bf16_t;
typedef bf16_t bf16x8 __attribute__((ext_vector_type(8)));
typedef bf16_t bf16x4 __attribute__((ext_vector_type(4)));
typedef float f32x4 __attribute__((ext_vector_type(4)));

typedef const __attribute__((address_space(1))) void GV;
typedef __attribute__((address_space(3))) void LV;

__device__ __forceinline__ void gload_lds16(const bf16_t* gsrc, bf16_t* ldst) {
    __builtin_amdgcn_global_load_lds((GV*)gsrc, (LV*)ldst, 16, 0, 0);
}

// ---------------- weight transpose+convert: in fp32 (K x N) -> out bf16 (N x K)
__global__ __launch_bounds__(256) void wtrans_kernel(const float* __restrict__ in,
                                                     bf16_t* __restrict__ out, int K, int N)
{
    __shared__ float tile[32][33];
    const int n0 = blockIdx.x * 32, k0 = blockIdx.y * 32;
    const int tx = threadIdx.x & 31, ty = threadIdx.x >> 5;  // 32 x 8
#pragma unroll
    for (int i = 0; i < 32; i += 8)
        tile[ty + i][tx] = in[(long long)(k0 + ty + i) * N + n0 + tx];
    __syncthreads();
#pragma unroll
    for (int i = 0; i < 32; i += 8)
        out[(long long)(n0 + ty + i) * K + k0 + tx] = (bf16_t)tile[tx][ty + i];
}

// ---------------- 6 modulation linears on cond: out[(sig*8+b)*512 + n]
__global__ __launch_bounds__(256) void modsig_kernel(
    const float* __restrict__ cond,
    const float* __restrict__ w0, const float* __restrict__ w1, const float* __restrict__ w2,
    const float* __restrict__ w3, const float* __restrict__ w4, const float* __restrict__ w5,
    const float* __restrict__ c0, const float* __restrict__ c1, const float* __restrict__ c2,
    const float* __restrict__ c3, const float* __restrict__ c4, const float* __restrict__ c5,
    float* __restrict__ out)
{
    __shared__ float cs[512];
    const int sig = blockIdx.x >> 3, b = blockIdx.x & 7;
    const float* w; const float* bi;
    switch (sig) {
        case 0: w = w0; bi = c0; break;
        case 1: w = w1; bi = c1; break;
        case 2: w = w2; bi = c2; break;
        case 3: w = w3; bi = c3; break;
        case 4: w = w4; bi = c4; break;
        default: w = w5; bi = c5; break;
    }
    for (int i = threadIdx.x; i < 512; i += 256) cs[i] = cond[b * 512 + i];
    __syncthreads();
    for (int n = threadIdx.x; n < 512; n += 256) {
        float s = bi[n];
        for (int i = 0; i < 512; ++i) s = fmaf(cs[i], w[(long long)i * 512 + n], s);
        out[(long long)(sig * 8 + b) * 512 + n] = s;
    }
}

// ---------------- fused LayerNorm + AdaLN modulate, fp32 -> bf16
__global__ __launch_bounds__(128) void ln_mod_kernel(
    const float* __restrict__ x, const float* __restrict__ g, const float* __restrict__ be,
    const float* __restrict__ gamma, const float* __restrict__ beta, bf16_t* __restrict__ out)
{
    const int row = blockIdx.x;
    const int b = row >> 10;
    const int t = threadIdx.x;
    const float4 v = reinterpret_cast<const float4*>(x + (long long)row * 512)[t];
    float s = v.x + v.y + v.z + v.w;
    float ss = v.x * v.x + v.y * v.y + v.z * v.z + v.w * v.w;
    for (int o = 32; o; o >>= 1) { s += __shfl_xor(s, o); ss += __shfl_xor(ss, o); }
    __shared__ float red[4];
    if ((t & 63) == 0) { red[t >> 6] = s; red[2 + (t >> 6)] = ss; }
    __syncthreads();
    s = red[0] + red[1]; ss = red[2] + red[3];
    const float mu = s * (1.f / 512.f);
    const float rstd = rsqrtf(ss * (1.f / 512.f) - mu * mu + 1e-5f);
    const float4 gv = reinterpret_cast<const float4*>(g)[t];
    const float4 bv = reinterpret_cast<const float4*>(be)[t];
    const float4 ga = reinterpret_cast<const float4*>(gamma + b * 512)[t];
    const float4 bb = reinterpret_cast<const float4*>(beta + b * 512)[t];
    bf16x4 ov;
    ov[0] = (bf16_t)(((v.x - mu) * rstd * gv.x + bv.x) * (1.f + ga.x) + bb.x);
    ov[1] = (bf16_t)(((v.y - mu) * rstd * gv.y + bv.y) * (1.f + ga.y) + bb.y);
    ov[2] = (bf16_t)(((v.z - mu) * rstd * gv.z + bv.z) * (1.f + ga.z) + bb.z);
    ov[3] = (bf16_t)(((v.w - mu) * rstd * gv.w + bv.w) * (1.f + ga.w) + bb.w);
    reinterpret_cast<bf16x4*>(out + (long long)row * 512)[t] = ov;
}

// ---------------- 128x128x32 bf16 MFMA GEMM via global_load_lds, C = A * B^T
template <int EPI>
__global__ __launch_bounds__(256) void gemm128_kernel(
    const bf16_t* __restrict__ A, const bf16_t* __restrict__ B,
    const float* __restrict__ bias, void* Cout,
    int M, int N, int K, int lda, int ldb, int ldc)
{
    const int m0 = blockIdx.y * 128, n0 = blockIdx.x * 128;
    const int tid = threadIdx.x, lane = tid & 63, wid = tid >> 6;
    const int wr = wid >> 1, wc = wid & 1;

    __shared__ bf16_t As[4096];
    __shared__ bf16_t Bs[4096];

    f32x4 acc[4][4];
#pragma unroll
    for (int m = 0; m < 4; ++m)
#pragma unroll
        for (int n = 0; n < 4; ++n) acc[m][n] = (f32x4){0.f, 0.f, 0.f, 0.f};

    const int r0 = wid * 16 + (lane >> 2);
    const int lc = (lane & 3) ^ ((lane >> 2) & 3);
    const long long aOff0 = (long long)(m0 + r0) * lda + lc * 8;
    const long long aOff1 = (long long)(m0 + r0 + 64) * lda + lc * 8;
    const long long bOff0 = (long long)(n0 + r0) * ldb + lc * 8;
    const long long bOff1 = (long long)(n0 + r0 + 64) * ldb + lc * 8;
    bf16_t* aDst0 = As + wid * 512;
    bf16_t* aDst1 = As + 2048 + wid * 512;
    bf16_t* bDst0 = Bs + wid * 512;
    bf16_t* bDst1 = Bs + 2048 + wid * 512;

    const int frow = lane & 15, lg = lane >> 4;
    const int pc = lg ^ (frow & 3);

    for (int kt = 0; kt < K; kt += 32) {
        gload_lds16(A + aOff0 + kt, aDst0);
        gload_lds16(A + aOff1 + kt, aDst1);
        gload_lds16(B + bOff0 + kt, bDst0);
        gload_lds16(B + bOff1 + kt, bDst1);
        __syncthreads();
        bf16x8 af[4], bfv[4];
#pragma unroll
        for (int m = 0; m < 4; ++m)
            af[m] = *reinterpret_cast<const bf16x8*>(As + (wr * 64 + m * 16 + frow) * 32 + pc * 8);
#pragma unroll
        for (int n = 0; n < 4; ++n)
            bfv[n] = *reinterpret_cast<const bf16x8*>(Bs + (wc * 64 + n * 16 + frow) * 32 + pc * 8);
        __builtin_amdgcn_s_setprio(1);
#pragma unroll
        for (int m = 0; m < 4; ++m)
#pragma unroll
            for (int n = 0; n < 4; ++n)
                acc[m][n] = __builtin_amdgcn_mfma_f32_16x16x32_bf16(af[m], bfv[n], acc[m][n], 0, 0, 0);
        __builtin_amdgcn_s_setprio(0);
        __syncthreads();
    }

#pragma unroll
    for (int m = 0; m < 4; ++m) {
        const int gm = m0 + wr * 64 + m * 16 + ((lane >> 4) << 2);
#pragma unroll
        for (int n = 0; n < 4; ++n) {
            const int gn = n0 + wc * 64 + n * 16 + (lane & 15);
            const float bb = bias ? bias[gn] : 0.f;
#pragma unroll
            for (int j = 0; j < 4; ++j) {
                const float v = acc[m][n][j] + bb;
                const int gmj = gm + j;
                if (EPI == 0) {
                    ((bf16_t*)Cout)[(long long)gmj * ldc + gn] = (bf16_t)v;
                } else {
                    ((bf16_t*)Cout)[(long long)gmj * ldc + gn] = (bf16_t)fmaxf(v, 0.f);
                }
            }
        }
    }
}

// ---------------- fused QKV GEMM: B = [wqT;wkT;wvT] (12288 x 512 contiguous)
// n-section 0 -> qb, 1 -> kb, 2 -> vtb (transposed-V (b,h,e,s) layout)
__global__ __launch_bounds__(256) void gemmqkv_kernel(
    const bf16_t* __restrict__ A, const bf16_t* __restrict__ B,
    const float* __restrict__ bq, const float* __restrict__ bk, const float* __restrict__ bv,
    bf16_t* __restrict__ qkv, bf16_t* __restrict__ vtb)
{
    const int m0 = blockIdx.y * 128, n0 = blockIdx.x * 128;
    const int sec = n0 >> 12;
    const float* bias = (sec == 0) ? bq : ((sec == 1) ? bk : bv);
    const int tid = threadIdx.x, lane = tid & 63, wid = tid >> 6;
    const int wr = wid >> 1, wc = wid & 1;

    __shared__ bf16_t As[4096];
    __shared__ bf16_t Bs[4096];

    f32x4 acc[4][4];
#pragma unroll
    for (int m = 0; m < 4; ++m)
#pragma unroll
        for (int n = 0; n < 4; ++n) acc[m][n] = (f32x4){0.f, 0.f, 0.f, 0.f};

    const int r0 = wid * 16 + (lane >> 2);
    const int lc = (lane & 3) ^ ((lane >> 2) & 3);
    const long long aOff0 = (long long)(m0 + r0) * 512 + lc * 8;
    const long long aOff1 = (long long)(m0 + r0 + 64) * 512 + lc * 8;
    const long long bOff0 = (long long)(n0 + r0) * 512 + lc * 8;
    const long long bOff1 = (long long)(n0 + r0 + 64) * 512 + lc * 8;
    bf16_t* aDst0 = As + wid * 512;
    bf16_t* aDst1 = As + 2048 + wid * 512;
    bf16_t* bDst0 = Bs + wid * 512;
    bf16_t* bDst1 = Bs + 2048 + wid * 512;

    const int frow = lane & 15, lg = lane >> 4;
    const int pc = lg ^ (frow & 3);

    for (int kt = 0; kt < 512; kt += 32) {
        gload_lds16(A + aOff0 + kt, aDst0);
        gload_lds16(A + aOff1 + kt, aDst1);
        gload_lds16(B + bOff0 + kt, bDst0);
        gload_lds16(B + bOff1 + kt, bDst1);
        __syncthreads();
        bf16x8 af[4], bfv[4];
#pragma unroll
        for (int m = 0; m < 4; ++m)
            af[m] = *reinterpret_cast<const bf16x8*>(As + (wr * 64 + m * 16 + frow) * 32 + pc * 8);
#pragma unroll
        for (int n = 0; n < 4; ++n)
            bfv[n] = *reinterpret_cast<const bf16x8*>(Bs + (wc * 64 + n * 16 + frow) * 32 + pc * 8);
        __builtin_amdgcn_s_setprio(1);
#pragma unroll
        for (int m = 0; m < 4; ++m)
#pragma unroll
            for (int n = 0; n < 4; ++n)
                acc[m][n] = __builtin_amdgcn_mfma_f32_16x16x32_bf16(af[m], bfv[n], acc[m][n], 0, 0, 0);
        __builtin_amdgcn_s_setprio(0);
        __syncthreads();
    }

#pragma unroll
    for (int m = 0; m < 4; ++m) {
        const int gm = m0 + wr * 64 + m * 16 + ((lane >> 4) << 2);
#pragma unroll
        for (int n = 0; n < 4; ++n) {
            const int gn = n0 + wc * 64 + n * 16 + (lane & 15);
            const int gnl = gn & 4095;
            const float bb = bias[gnl];
#pragma unroll
            for (int j = 0; j < 4; ++j) {
                const float v = acc[m][n][j] + bb;
                const int gmj = gm + j;
                if (sec < 2) {
                    qkv[(long long)sec * 33554432 + (long long)gmj * 4096 + gnl] = (bf16_t)v;
                } else {
                    const long long ci =
                        (long long)(((gmj >> 10) * 8 + (gnl >> 9)) * 512 + (gnl & 511)) * 1024 + (gmj & 1023);
                    vtb[ci] = (bf16_t)v;
                }
            }
        }
    }
}

// ---------------- 64x128x32 GEMM via global_load_lds, out = resid + (acc+bias)*alpha
__global__ __launch_bounds__(256) void gemm64_kernel(
    const bf16_t* __restrict__ A, const bf16_t* __restrict__ B,
    const float* __restrict__ bias, float* __restrict__ Cout,
    const float* __restrict__ resid, const float* __restrict__ alpha,
    int M, int N, int K, int lda, int ldb)
{
    const int m0 = blockIdx.y * 64, n0 = blockIdx.x * 128;
    const int tid = threadIdx.x, lane = tid & 63, wid = tid >> 6;
    const int wr = wid >> 1, wc = wid & 1;

    __shared__ bf16_t As[2048];
    __shared__ bf16_t Bs[4096];

    f32x4 acc[2][4];
#pragma unroll
    for (int m = 0; m < 2; ++m)
#pragma unroll
        for (int n = 0; n < 4; ++n) acc[m][n] = (f32x4){0.f, 0.f, 0.f, 0.f};

    const int r0 = wid * 16 + (lane >> 2);
    const int lc = (lane & 3) ^ ((lane >> 2) & 3);
    const long long aOff0 = (long long)(m0 + r0) * lda + lc * 8;
    const long long bOff0 = (long long)(n0 + r0) * ldb + lc * 8;
    const long long bOff1 = (long long)(n0 + r0 + 64) * ldb + lc * 8;
    bf16_t* aDst0 = As + wid * 512;
    bf16_t* bDst0 = Bs + wid * 512;
    bf16_t* bDst1 = Bs + 2048 + wid * 512;

    const int frow = lane & 15, lg = lane >> 4;
    const int pc = lg ^ (frow & 3);

    for (int kt = 0; kt < K; kt += 32) {
        gload_lds16(A + aOff0 + kt, aDst0);
        gload_lds16(B + bOff0 + kt, bDst0);
        gload_lds16(B + bOff1 + kt, bDst1);
        __syncthreads();
        bf16x8 af[2], bfv[4];
#pragma unroll
        for (int m = 0; m < 2; ++m)
            af[m] = *reinterpret_cast<const bf16x8*>(As + (wr * 32 + m * 16 + frow) * 32 + pc * 8);
#pragma unroll
        for (int n = 0; n < 4; ++n)
            bfv[n] = *reinterpret_cast<const bf16x8*>(Bs + (wc * 64 + n * 16 + frow) * 32 + pc * 8);
        __builtin_amdgcn_s_setprio(1);
#pragma unroll
        for (int m = 0; m < 2; ++m)
#pragma unroll
            for (int n = 0; n < 4; ++n)
                acc[m][n] = __builtin_amdgcn_mfma_f32_16x16x32_bf16(af[m], bfv[n], acc[m][n], 0, 0, 0);
        __builtin_amdgcn_s_setprio(0);
        __syncthreads();
    }

#pragma unroll
    for (int m = 0; m < 2; ++m) {
        const int gm = m0 + wr * 32 + m * 16 + ((lane >> 4) << 2);
#pragma unroll
        for (int n = 0; n < 4; ++n) {
            const int gn = n0 + wc * 64 + n * 16 + (lane & 15);
            const float bb = bias[gn];
#pragma unroll
            for (int j = 0; j < 4; ++j) {
                const int gmj = gm + j;
                const long long ci = (long long)gmj * 512 + gn;
                Cout[ci] = resid[ci] + (acc[m][n][j] + bb) * alpha[(gmj >> 10) * 512 + gn];
            }
        }
    }
}

// ---------------- fused flash attention v5 = round-4 v2 with K/V time-sharing ONE
// 64KB LDS buffer (LDS 141KB -> 74KB => 2 blocks/CU). 4 barriers/iter; cross-block
// overlap covers the exposed K/V DMA drains. Math identical to v2 (verified).
#define FA_LDS 75776
#define SCL 0.04508422132207354f   /* (1/32) * log2(e) */
__global__ __launch_bounds__(512, 2) void flash_kernel(
    bf16_t* __restrict__ qb, const bf16_t* __restrict__ kb, const bf16_t* __restrict__ vtb)
{
    extern __shared__ char smem[];
    bf16_t* KVs = (bf16_t*)smem;                // K: [64][512] chunk16^(row&7) | V: [512][64] chunk16^(e&7)
    char* PB = smem + 65536;                    // [64 q][64 k] bf16, 8B gran ^ ((q&7)<<1)
    float* pmaxB = (float*)(smem + 73728);      // [2][2][64]
    float* psumB = (float*)(smem + 74752);      // [2][2][64]

    const int bid = blockIdx.x;
    const int xcd = bid & 7, idx = bid >> 3;
    const int qt = idx & 15, bhl = idx >> 4;
    const int bh = xcd * 8 + bhl;
    const int b = bh >> 3, h = bh & 7;
    const int q0 = qt * 64;
    const int tid = threadIdx.x, lane = tid & 63, wid = tid >> 6;
    const int laneq = lane & 15, lx = lane & 7, lg = lane >> 4;
    const int wk = wid >> 2, wq = wid & 3;      // S role
    const int we = wid & 3, wq2 = wid >> 2;     // PV role

    // ---- prologue: stage K(0); load Q frags to registers
#pragma unroll
    for (int r = 0; r < 8; ++r) {
        const int row = r * 8 + wid;
        gload_lds16(kb + ((long long)(b * 1024 + row) * 8 + h) * 512 + ((lane ^ (row & 7)) << 3),
                    KVs + row * 512);
    }
    const int qi = wq * 16 + laneq;
    bf16x8 qfrag[16];
    {
        const bf16_t* qrow = qb + ((long long)(b * 1024 + q0 + qi) * 8 + h) * 512 + lg * 8;
#pragma unroll
        for (int ks = 0; ks < 16; ++ks) qfrag[ks] = *reinterpret_cast<const bf16x8*>(qrow + ks * 32);
    }
    f32x4 accA[8], accB[8];
#pragma unroll
    for (int e = 0; e < 8; ++e) { accA[e] = (f32x4){0.f,0.f,0.f,0.f}; accB[e] = (f32x4){0.f,0.f,0.f,0.f}; }
    float mS = 0.f, mPA = 0.f, mPB = 0.f, lA = 0.f, lB = 0.f;
    const int rA0 = wk * 32 + laneq, rA1 = rA0 + 16;
    const int qA = wq2 * 32 + laneq, qB = qA + 16;
    const int qx = (qi & 7) << 1;
    const int qxA = (qA & 7) << 1, qxB = (qB & 7) << 1;

    for (int t = 0; t < 16; ++t) {
        __syncthreads();  // (D): K(t) landed (vmcnt drained by compiler before barrier)
        // (b) S-phase: S^T = K · Q^T
        f32x4 s0 = (f32x4){0.f,0.f,0.f,0.f}, s1 = (f32x4){0.f,0.f,0.f,0.f};
        const char* KsB = (const char*)KVs;
        __builtin_amdgcn_s_setprio(1);
#pragma unroll
        for (int ks = 0; ks < 16; ++ks) {
            const int co = ((ks * 4 + lg) ^ lx) << 4;
            bf16x8 a0 = *(const bf16x8*)(KsB + rA0 * 1024 + co);
            bf16x8 a1 = *(const bf16x8*)(KsB + rA1 * 1024 + co);
            s0 = __builtin_amdgcn_mfma_f32_16x16x32_bf16(a0, qfrag[ks], s0, 0, 0, 0);
            s1 = __builtin_amdgcn_mfma_f32_16x16x32_bf16(a1, qfrag[ks], s1, 0, 0, 0);
        }
        __builtin_amdgcn_s_setprio(0);
        // (c) delayed-max softmax partials (registers only)
        float f[8];
#pragma unroll
        for (int j = 0; j < 4; ++j) { f[j] = s0[j] * SCL; f[4 + j] = s1[j] * SCL; }
        float mloc = f[0];
#pragma unroll
        for (int j = 1; j < 8; ++j) mloc = fmaxf(mloc, f[j]);
        mloc = fmaxf(mloc, __shfl_xor(mloc, 16));
        mloc = fmaxf(mloc, __shfl_xor(mloc, 32));
        float pe[8]; float sl = 0.f;
#pragma unroll
        for (int j = 0; j < 8; ++j) { pe[j] = exp2f(f[j] - mS); sl += pe[j]; }
        sl += __shfl_xor(sl, 16);
        sl += __shfl_xor(sl, 32);
        __syncthreads();  // (A): all K reads done -> buffer free for V
        // (a) stage V(t) into the shared buffer
#pragma unroll
        for (int r = 0; r < 8; ++r) {
            const int e = r * 64 + wid * 8 + (lane >> 3);
            gload_lds16(vtb + ((long long)bh * 512 + e) * 1024 + t * 64 + ((lx ^ (e & 7)) << 3),
                        KVs + (r * 64 + wid * 8) * 64);
        }
        // write P + stats (PB/stat regions, disjoint from KVs)
        if (lane < 16) {
            pmaxB[(t & 1) * 128 + wk * 64 + wq * 16 + lane] = mloc;
            psumB[(t & 1) * 128 + wk * 64 + wq * 16 + lane] = sl;
        }
        {
            bf16x4 p0, p1;
#pragma unroll
            for (int j = 0; j < 4; ++j) { p0[j] = (bf16_t)pe[j]; p1[j] = (bf16_t)pe[4 + j]; }
            const int kc0 = wk * 8 + lg, kc1 = kc0 + 4;
            *(bf16x4*)(PB + qi * 128 + ((kc0 ^ qx) << 3)) = p0;
            *(bf16x4*)(PB + qi * 128 + ((kc1 ^ qx) << 3)) = p1;
        }
        __syncthreads();  // (B): V landed, P + stats visible
        // (f) PV
        const char* VB = (const char*)KVs;
        __builtin_amdgcn_s_setprio(1);
#pragma unroll
        for (int ks2 = 0; ks2 < 2; ++ks2) {
            const int kcp = ks2 * 8 + lg * 2;
            bf16x8 pA = *(const bf16x8*)(PB + qA * 128 + ((kcp ^ qxA) << 3));
            bf16x8 pBv = *(const bf16x8*)(PB + qB * 128 + ((kcp ^ qxB) << 3));
            const int kcv = ks2 * 4 + lg;
#pragma unroll
            for (int ef = 0; ef < 8; ++ef) {
                const int re = we * 128 + ef * 16 + laneq;
                bf16x8 av = *(const bf16x8*)(VB + re * 128 + ((kcv ^ lx) << 4));
                accA[ef] = __builtin_amdgcn_mfma_f32_16x16x32_bf16(av, pA, accA[ef], 0, 0, 0);
                accB[ef] = __builtin_amdgcn_mfma_f32_16x16x32_bf16(av, pBv, accB[ef], 0, 0, 0);
            }
        }
        __builtin_amdgcn_s_setprio(0);
        // stats: accumulate in old units, then rescale to new max
        {
            const float* pmax_t = pmaxB + (t & 1) * 128;
            const float* psum_t = psumB + (t & 1) * 128;
            mS = fmaxf(mS, fmaxf(pmax_t[qi], pmax_t[64 + qi]));
            lA += psum_t[qA] + psum_t[64 + qA];
            lB += psum_t[qB] + psum_t[64 + qB];
            const float mnA = fmaxf(mPA, fmaxf(pmax_t[qA], pmax_t[64 + qA]));
            const float mnB = fmaxf(mPB, fmaxf(pmax_t[qB], pmax_t[64 + qB]));
            if (__ballot((mnA > mPA) || (mnB > mPB))) {
                const float rA = exp2f(mPA - mnA), rB = exp2f(mPB - mnB);
                lA *= rA; lB *= rB;
#pragma unroll
                for (int e = 0; e < 8; ++e) {
#pragma unroll
                    for (int j = 0; j < 4; ++j) { accA[e][j] *= rA; accB[e][j] *= rB; }
                }
            }
            mPA = mnA; mPB = mnB;
        }
        __syncthreads();  // (C): V reads + P reads done -> buffer free for K(t+1)
        // (e) stage K(t+1)
        if (t < 15) {
#pragma unroll
            for (int r = 0; r < 8; ++r) {
                const int row = r * 8 + wid;
                gload_lds16(kb + ((long long)(b * 1024 + t * 64 + 64 + row) * 8 + h) * 512
                                + ((lane ^ (row & 7)) << 3),
                            KVs + row * 512);
            }
        }
    }

    // ---- epilogue: O = acc / l, store over qb
    const float iA = 1.f / lA, iB = 1.f / lB;
#pragma unroll
    for (int ef = 0; ef < 8; ++ef) {
        const int e0 = we * 128 + ef * 16 + lg * 4;
        bf16x4 oA, oB;
#pragma unroll
        for (int j = 0; j < 4; ++j) { oA[j] = (bf16_t)(accA[ef][j] * iA); oB[j] = (bf16_t)(accB[ef][j] * iB); }
        *(bf16x4*)(qb + ((long long)(b * 1024 + q0 + qA) * 8 + h) * 512 + e0) = oA;
        *(bf16x4*)(qb + ((long long)(b * 1024 + q0 + qB) * 8 + h) * 512 + e0) = oB;
    }
}

extern "C" void kernel_launch(void* const* d_in, const int* in_sizes, int n_in,
                              void* d_out, int out_size, void* d_ws, size_t ws_size,
                              hipStream_t stream)
{
    const float* x    = (const float*)d_in[0];
    const float* cond = (const float*)d_in[1];
    const float* g1w  = (const float*)d_in[2];  const float* g1b  = (const float*)d_in[3];
    const float* be1w = (const float*)d_in[4];  const float* be1b = (const float*)d_in[5];
    const float* a1w  = (const float*)d_in[6];  const float* a1b  = (const float*)d_in[7];
    const float* g2w  = (const float*)d_in[8];  const float* g2b  = (const float*)d_in[9];
    const float* be2w = (const float*)d_in[10]; const float* be2b = (const float*)d_in[11];
    const float* a2w  = (const float*)d_in[12]; const float* a2b  = (const float*)d_in[13];
    const float* ln1g = (const float*)d_in[14]; const float* ln1b = (const float*)d_in[15];
    const float* ln2g = (const float*)d_in[16]; const float* ln2b = (const float*)d_in[17];
    const float* wq   = (const float*)d_in[18]; const float* bq   = (const float*)d_in[19];
    const float* wk   = (const float*)d_in[20]; const float* bk   = (const float*)d_in[21];
    const float* wv   = (const float*)d_in[22]; const float* bv   = (const float*)d_in[23];
    const float* lvw  = (const float*)d_in[24]; const float* lvb  = (const float*)d_in[25];
    const float* f1w  = (const float*)d_in[26]; const float* f1b  = (const float*)d_in[27];
    const float* f2w  = (const float*)d_in[28]; const float* f2b  = (const float*)d_in[29];
    (void)in_sizes; (void)n_in; (void)out_size; (void)ws_size;

    // workspace layout (bytes)
    char* w8 = (char*)d_ws;
    float*  mod  = (float*)(w8);                                   //  98304
    bf16_t* wqT  = (bf16_t*)(w8 + 98304);                          // 4096x512 bf16 (wq/wk/wv contiguous)
    bf16_t* lvwT = (bf16_t*)(w8 + 98304 + 3 * 4194304);            // 512x4096
    bf16_t* f1wT = (bf16_t*)(w8 + 98304 + 4 * 4194304);            // 2048x512
    bf16_t* f2wT = (bf16_t*)(w8 + 98304 + 4 * 4194304 + 2097152);  // 512x2048
    bf16_t* ybf  = (bf16_t*)(w8 + 98304 + 4 * 4194304 + 2 * 2097152);           // 8192x512
    bf16_t* qb   = (bf16_t*)(w8 + 98304 + 4 * 4194304 + 2 * 2097152 + 8388608); // (b,s,h,e); O in place
    bf16_t* kb   = qb + 33554432;    // (b,s,h,e)
    bf16_t* vtb  = kb + 33554432;    // V transposed: (b,h,e,s)

    (void)hipFuncSetAttribute((const void*)flash_kernel,
                              hipFuncAttributeMaxDynamicSharedMemorySize, FA_LDS);

    const dim3 blk(256);
    // weights -> bf16 transposed
    wtrans_kernel<<<dim3(128, 16), blk, 0, stream>>>(wq, wqT, 512, 4096);
    wtrans_kernel<<<dim3(128, 16), blk, 0, stream>>>(wk, wqT + 2097152, 512, 4096);
    wtrans_kernel<<<dim3(128, 16), blk, 0, stream>>>(wv, wqT + 2 * 2097152, 512, 4096);
    wtrans_kernel<<<dim3(16, 128), blk, 0, stream>>>(lvw, lvwT, 4096, 512);
    wtrans_kernel<<<dim3(64, 16), blk, 0, stream>>>(f1w, f1wT, 512, 2048);
    wtrans_kernel<<<dim3(16, 64), blk, 0, stream>>>(f2w, f2wT, 2048, 512);
    // modulation signals
    modsig_kernel<<<48, blk, 0, stream>>>(cond, g1w, be1w, a1w, g2w, be2w, a2w,
                                          g1b, be1b, a1b, g2b, be2b, a2b, mod);
    // LN1 + modulate -> y (bf16)
    ln_mod_kernel<<<8192, 128, 0, stream>>>(x, ln1g, ln1b, mod, mod + 4096, ybf);
    // fused QKV projection (V stored transposed)
    gemmqkv_kernel<<<dim3(96, 64), blk, 0, stream>>>(ybf, wqT, bq, bk, bv, qb, vtb);
    // fused flash attention: O overwrites qb
    flash_kernel<<<1024, 512, FA_LDS, stream>>>(qb, kb, vtb);
    // y2 = x + (O @ lvw + lvb) * alpha1 -> d_out (fp32)
    gemm64_kernel<<<dim3(4, 128), blk, 0, stream>>>(qb, lvwT, lvb, (float*)d_out, x, mod + 8192,
        8192, 512, 4096, 4096, 4096);
    // LN2 + modulate -> z (bf16)
    ln_mod_kernel<<<8192, 128, 0, stream>>>((const float*)d_out, ln2g, ln2b,
                                            mod + 12288, mod + 16384, ybf);
    // FFN
    gemm128_kernel<1><<<dim3(16, 64), blk, 0, stream>>>(ybf, f1wT, f1b, qb,
        8192, 2048, 512, 512, 512, 2048);
    gemm64_kernel<<<dim3(4, 128), blk, 0, stream>>>(qb, f2wT, f2b, (float*)d_out,
        (const float*)d_out, mod + 20480,
        8192, 512, 2048, 2048, 2048);
}

// Round 8
// 691.619 us; speedup vs baseline: 1.3091x; 1.0816x over previous
//
#include <hip/hip_runtime.h>
#include <hip/hip_bf16.h>

typedef __bf16 bf16_t;
typedef bf16_t bf16x8 __attribute__((ext_vector_type(8)));
typedef bf16_t bf16x4 __attribute__((ext_vector_type(4)));
typedef float f32x4 __attribute__((ext_vector_type(4)));

typedef const __attribute__((address_space(1))) void GV;
typedef __attribute__((address_space(3))) void LV;

__device__ __forceinline__ void gload_lds16(const bf16_t* gsrc, bf16_t* ldst) {
    __builtin_amdgcn_global_load_lds((GV*)gsrc, (LV*)ldst, 16, 0, 0);
}

// ---------------- weight transpose+convert: in fp32 (K x N) -> out bf16 (N x K)
__global__ __launch_bounds__(256) void wtrans_kernel(const float* __restrict__ in,
                                                     bf16_t* __restrict__ out, int K, int N)
{
    __shared__ float tile[32][33];
    const int n0 = blockIdx.x * 32, k0 = blockIdx.y * 32;
    const int tx = threadIdx.x & 31, ty = threadIdx.x >> 5;  // 32 x 8
#pragma unroll
    for (int i = 0; i < 32; i += 8)
        tile[ty + i][tx] = in[(long long)(k0 + ty + i) * N + n0 + tx];
    __syncthreads();
#pragma unroll
    for (int i = 0; i < 32; i += 8)
        out[(long long)(n0 + ty + i) * K + k0 + tx] = (bf16_t)tile[tx][ty + i];
}

// ---------------- 6 modulation linears on cond: out[(sig*8+b)*512 + n]
__global__ __launch_bounds__(256) void modsig_kernel(
    const float* __restrict__ cond,
    const float* __restrict__ w0, const float* __restrict__ w1, const float* __restrict__ w2,
    const float* __restrict__ w3, const float* __restrict__ w4, const float* __restrict__ w5,
    const float* __restrict__ c0, const float* __restrict__ c1, const float* __restrict__ c2,
    const float* __restrict__ c3, const float* __restrict__ c4, const float* __restrict__ c5,
    float* __restrict__ out)
{
    __shared__ float cs[512];
    const int sig = blockIdx.x >> 3, b = blockIdx.x & 7;
    const float* w; const float* bi;
    switch (sig) {
        case 0: w = w0; bi = c0; break;
        case 1: w = w1; bi = c1; break;
        case 2: w = w2; bi = c2; break;
        case 3: w = w3; bi = c3; break;
        case 4: w = w4; bi = c4; break;
        default: w = w5; bi = c5; break;
    }
    for (int i = threadIdx.x; i < 512; i += 256) cs[i] = cond[b * 512 + i];
    __syncthreads();
    for (int n = threadIdx.x; n < 512; n += 256) {
        float s = bi[n];
        for (int i = 0; i < 512; ++i) s = fmaf(cs[i], w[(long long)i * 512 + n], s);
        out[(long long)(sig * 8 + b) * 512 + n] = s;
    }
}

// ---------------- fused LayerNorm + AdaLN modulate, fp32 -> bf16
__global__ __launch_bounds__(128) void ln_mod_kernel(
    const float* __restrict__ x, const float* __restrict__ g, const float* __restrict__ be,
    const float* __restrict__ gamma, const float* __restrict__ beta, bf16_t* __restrict__ out)
{
    const int row = blockIdx.x;
    const int b = row >> 10;
    const int t = threadIdx.x;
    const float4 v = reinterpret_cast<const float4*>(x + (long long)row * 512)[t];
    float s = v.x + v.y + v.z + v.w;
    float ss = v.x * v.x + v.y * v.y + v.z * v.z + v.w * v.w;
    for (int o = 32; o; o >>= 1) { s += __shfl_xor(s, o); ss += __shfl_xor(ss, o); }
    __shared__ float red[4];
    if ((t & 63) == 0) { red[t >> 6] = s; red[2 + (t >> 6)] = ss; }
    __syncthreads();
    s = red[0] + red[1]; ss = red[2] + red[3];
    const float mu = s * (1.f / 512.f);
    const float rstd = rsqrtf(ss * (1.f / 512.f) - mu * mu + 1e-5f);
    const float4 gv = reinterpret_cast<const float4*>(g)[t];
    const float4 bv = reinterpret_cast<const float4*>(be)[t];
    const float4 ga = reinterpret_cast<const float4*>(gamma + b * 512)[t];
    const float4 bb = reinterpret_cast<const float4*>(beta + b * 512)[t];
    bf16x4 ov;
    ov[0] = (bf16_t)(((v.x - mu) * rstd * gv.x + bv.x) * (1.f + ga.x) + bb.x);
    ov[1] = (bf16_t)(((v.y - mu) * rstd * gv.y + bv.y) * (1.f + ga.y) + bb.y);
    ov[2] = (bf16_t)(((v.z - mu) * rstd * gv.z + bv.z) * (1.f + ga.z) + bb.z);
    ov[3] = (bf16_t)(((v.w - mu) * rstd * gv.w + bv.w) * (1.f + ga.w) + bb.w);
    reinterpret_cast<bf16x4*>(out + (long long)row * 512)[t] = ov;
}

// ---------------- 128x128x64 bf16 MFMA GEMM (BK=64), C = A * B^T, XCD-swizzled grid
// EPI 0: bf16 store (+bias)  EPI 1: relu->bf16 (+bias)
template <int EPI>
__global__ __launch_bounds__(256) void gemm128_kernel(
    const bf16_t* __restrict__ A, const bf16_t* __restrict__ B,
    const float* __restrict__ bias, void* Cout,
    int M, int N, int K, int lda, int ldb, int ldc)
{
    const int nbx = gridDim.x;
    const int lin = blockIdx.y * nbx + blockIdx.x;
    const int cpx = (nbx * gridDim.y) >> 3;
    const int swz = (lin & 7) * cpx + (lin >> 3);
    const int m0 = (swz / nbx) * 128, n0 = (swz % nbx) * 128;
    const int tid = threadIdx.x, lane = tid & 63, wid = tid >> 6;
    const int wr = wid >> 1, wc = wid & 1;

    __shared__ bf16_t As[8192];
    __shared__ bf16_t Bs[8192];

    f32x4 acc[4][4];
#pragma unroll
    for (int m = 0; m < 4; ++m)
#pragma unroll
        for (int n = 0; n < 4; ++n) acc[m][n] = (f32x4){0.f, 0.f, 0.f, 0.f};

    const int r8 = lane >> 3;
    const int lc = (lane & 7) ^ r8;
    long long aOff[4], bOff[4];
#pragma unroll
    for (int i = 0; i < 4; ++i) {
        const int row = i * 32 + wid * 8 + r8;
        aOff[i] = (long long)(m0 + row) * lda + lc * 8;
        bOff[i] = (long long)(n0 + row) * ldb + lc * 8;
    }

    const int frow = lane & 15, lg = lane >> 4;
    const int p0 = lg ^ (frow & 7);

    for (int kt = 0; kt < K; kt += 64) {
#pragma unroll
        for (int i = 0; i < 4; ++i) gload_lds16(A + aOff[i] + kt, As + i * 2048 + wid * 512);
#pragma unroll
        for (int i = 0; i < 4; ++i) gload_lds16(B + bOff[i] + kt, Bs + i * 2048 + wid * 512);
        __syncthreads();
        __builtin_amdgcn_s_setprio(1);
#pragma unroll
        for (int kk = 0; kk < 2; ++kk) {
            const int pc = p0 ^ (kk << 2);
            bf16x8 af[4], bfv[4];
#pragma unroll
            for (int m = 0; m < 4; ++m)
                af[m] = *reinterpret_cast<const bf16x8*>(As + (wr * 64 + m * 16 + frow) * 64 + pc * 8);
#pragma unroll
            for (int n = 0; n < 4; ++n)
                bfv[n] = *reinterpret_cast<const bf16x8*>(Bs + (wc * 64 + n * 16 + frow) * 64 + pc * 8);
#pragma unroll
            for (int m = 0; m < 4; ++m)
#pragma unroll
                for (int n = 0; n < 4; ++n)
                    acc[m][n] = __builtin_amdgcn_mfma_f32_16x16x32_bf16(af[m], bfv[n], acc[m][n], 0, 0, 0);
        }
        __builtin_amdgcn_s_setprio(0);
        __syncthreads();
    }

#pragma unroll
    for (int m = 0; m < 4; ++m) {
        const int gm = m0 + wr * 64 + m * 16 + ((lane >> 4) << 2);
#pragma unroll
        for (int n = 0; n < 4; ++n) {
            const int gn = n0 + wc * 64 + n * 16 + (lane & 15);
            const float bb = bias ? bias[gn] : 0.f;
#pragma unroll
            for (int j = 0; j < 4; ++j) {
                const float v = acc[m][n][j] + bb;
                const int gmj = gm + j;
                if (EPI == 0) {
                    ((bf16_t*)Cout)[(long long)gmj * ldc + gn] = (bf16_t)v;
                } else {
                    ((bf16_t*)Cout)[(long long)gmj * ldc + gn] = (bf16_t)fmaxf(v, 0.f);
                }
            }
        }
    }
}

// ---------------- fused QKV GEMM (BK=64, XCD-swizzled): B = [wqT;wkT;wvT] (12288x512)
// n-section 0 -> qb, 1 -> kb, 2 -> vtb (transposed-V (b,h,e,s) layout)
__global__ __launch_bounds__(256) void gemmqkv_kernel(
    const bf16_t* __restrict__ A, const bf16_t* __restrict__ B,
    const float* __restrict__ bq, const float* __restrict__ bk, const float* __restrict__ bv,
    bf16_t* __restrict__ qkv, bf16_t* __restrict__ vtb)
{
    const int lin = blockIdx.y * 96 + blockIdx.x;
    const int swz = (lin & 7) * 768 + (lin >> 3);
    const int m0 = (swz / 96) * 128, n0 = (swz % 96) * 128;
    const int sec = n0 >> 12;
    const float* bias = (sec == 0) ? bq : ((sec == 1) ? bk : bv);
    const int tid = threadIdx.x, lane = tid & 63, wid = tid >> 6;
    const int wr = wid >> 1, wc = wid & 1;

    __shared__ bf16_t As[8192];
    __shared__ bf16_t Bs[8192];

    f32x4 acc[4][4];
#pragma unroll
    for (int m = 0; m < 4; ++m)
#pragma unroll
        for (int n = 0; n < 4; ++n) acc[m][n] = (f32x4){0.f, 0.f, 0.f, 0.f};

    const int r8 = lane >> 3;
    const int lc = (lane & 7) ^ r8;
    long long aOff[4], bOff[4];
#pragma unroll
    for (int i = 0; i < 4; ++i) {
        const int row = i * 32 + wid * 8 + r8;
        aOff[i] = (long long)(m0 + row) * 512 + lc * 8;
        bOff[i] = (long long)(n0 + row) * 512 + lc * 8;
    }

    const int frow = lane & 15, lg = lane >> 4;
    const int p0 = lg ^ (frow & 7);

    for (int kt = 0; kt < 512; kt += 64) {
#pragma unroll
        for (int i = 0; i < 4; ++i) gload_lds16(A + aOff[i] + kt, As + i * 2048 + wid * 512);
#pragma unroll
        for (int i = 0; i < 4; ++i) gload_lds16(B + bOff[i] + kt, Bs + i * 2048 + wid * 512);
        __syncthreads();
        __builtin_amdgcn_s_setprio(1);
#pragma unroll
        for (int kk = 0; kk < 2; ++kk) {
            const int pc = p0 ^ (kk << 2);
            bf16x8 af[4], bfv[4];
#pragma unroll
            for (int m = 0; m < 4; ++m)
                af[m] = *reinterpret_cast<const bf16x8*>(As + (wr * 64 + m * 16 + frow) * 64 + pc * 8);
#pragma unroll
            for (int n = 0; n < 4; ++n)
                bfv[n] = *reinterpret_cast<const bf16x8*>(Bs + (wc * 64 + n * 16 + frow) * 64 + pc * 8);
#pragma unroll
            for (int m = 0; m < 4; ++m)
#pragma unroll
                for (int n = 0; n < 4; ++n)
                    acc[m][n] = __builtin_amdgcn_mfma_f32_16x16x32_bf16(af[m], bfv[n], acc[m][n], 0, 0, 0);
        }
        __builtin_amdgcn_s_setprio(0);
        __syncthreads();
    }

#pragma unroll
    for (int m = 0; m < 4; ++m) {
        const int gm = m0 + wr * 64 + m * 16 + ((lane >> 4) << 2);
#pragma unroll
        for (int n = 0; n < 4; ++n) {
            const int gn = n0 + wc * 64 + n * 16 + (lane & 15);
            const int gnl = gn & 4095;
            const float bb = bias[gnl];
#pragma unroll
            for (int j = 0; j < 4; ++j) {
                const float v = acc[m][n][j] + bb;
                const int gmj = gm + j;
                if (sec < 2) {
                    qkv[(long long)sec * 33554432 + (long long)gmj * 4096 + gnl] = (bf16_t)v;
                } else {
                    const long long ci =
                        (long long)(((gmj >> 10) * 8 + (gnl >> 9)) * 512 + (gnl & 511)) * 1024 + (gmj & 1023);
                    vtb[ci] = (bf16_t)v;
                }
            }
        }
    }
}

// ---------------- 64x128x64 GEMM (BK=64, XCD-swizzled), out = resid + (acc+bias)*alpha
__global__ __launch_bounds__(256) void gemm64_kernel(
    const bf16_t* __restrict__ A, const bf16_t* __restrict__ B,
    const float* __restrict__ bias, float* __restrict__ Cout,
    const float* __restrict__ resid, const float* __restrict__ alpha,
    int M, int N, int K, int lda, int ldb)
{
    const int nbx = gridDim.x;
    const int lin = blockIdx.y * nbx + blockIdx.x;
    const int cpx = (nbx * gridDim.y) >> 3;
    const int swz = (lin & 7) * cpx + (lin >> 3);
    const int m0 = (swz / nbx) * 64, n0 = (swz % nbx) * 128;
    const int tid = threadIdx.x, lane = tid & 63, wid = tid >> 6;
    const int wr = wid >> 1, wc = wid & 1;

    __shared__ bf16_t As[4096];
    __shared__ bf16_t Bs[8192];

    f32x4 acc[2][4];
#pragma unroll
    for (int m = 0; m < 2; ++m)
#pragma unroll
        for (int n = 0; n < 4; ++n) acc[m][n] = (f32x4){0.f, 0.f, 0.f, 0.f};

    const int r8 = lane >> 3;
    const int lc = (lane & 7) ^ r8;
    long long aOff[2], bOff[4];
#pragma unroll
    for (int i = 0; i < 2; ++i)
        aOff[i] = (long long)(m0 + i * 32 + wid * 8 + r8) * lda + lc * 8;
#pragma unroll
    for (int i = 0; i < 4; ++i)
        bOff[i] = (long long)(n0 + i * 32 + wid * 8 + r8) * ldb + lc * 8;

    const int frow = lane & 15, lg = lane >> 4;
    const int p0 = lg ^ (frow & 7);

    for (int kt = 0; kt < K; kt += 64) {
#pragma unroll
        for (int i = 0; i < 2; ++i) gload_lds16(A + aOff[i] + kt, As + i * 2048 + wid * 512);
#pragma unroll
        for (int i = 0; i < 4; ++i) gload_lds16(B + bOff[i] + kt, Bs + i * 2048 + wid * 512);
        __syncthreads();
        __builtin_amdgcn_s_setprio(1);
#pragma unroll
        for (int kk = 0; kk < 2; ++kk) {
            const int pc = p0 ^ (kk << 2);
            bf16x8 af[2], bfv[4];
#pragma unroll
            for (int m = 0; m < 2; ++m)
                af[m] = *reinterpret_cast<const bf16x8*>(As + (wr * 32 + m * 16 + frow) * 64 + pc * 8);
#pragma unroll
            for (int n = 0; n < 4; ++n)
                bfv[n] = *reinterpret_cast<const bf16x8*>(Bs + (wc * 64 + n * 16 + frow) * 64 + pc * 8);
#pragma unroll
            for (int m = 0; m < 2; ++m)
#pragma unroll
                for (int n = 0; n < 4; ++n)
                    acc[m][n] = __builtin_amdgcn_mfma_f32_16x16x32_bf16(af[m], bfv[n], acc[m][n], 0, 0, 0);
        }
        __builtin_amdgcn_s_setprio(0);
        __syncthreads();
    }

#pragma unroll
    for (int m = 0; m < 2; ++m) {
        const int gm = m0 + wr * 32 + m * 16 + ((lane >> 4) << 2);
#pragma unroll
        for (int n = 0; n < 4; ++n) {
            const int gn = n0 + wc * 64 + n * 16 + (lane & 15);
            const float bb = bias[gn];
#pragma unroll
            for (int j = 0; j < 4; ++j) {
                const int gmj = gm + j;
                const long long ci = (long long)gmj * 512 + gn;
                Cout[ci] = resid[ci] + (acc[m][n][j] + bb) * alpha[(gmj >> 10) * 512 + gn];
            }
        }
    }
}

// ---------------- fused flash attention (round-4 v2, verified 320 us)
// Q in registers; K/V in separate LDS buffers; 2 barriers/iter pipeline:
//   V(t)-load || S-phase ; K(t+1)-load || PV-phase
// delayed running max (m through tile t-1), double-buffered pmax/psum.
#define FA_LDS 141312
#define SCL 0.04508422132207354f   /* (1/32) * log2(e) */
__global__ __launch_bounds__(512, 2) void flash_kernel(
    bf16_t* __restrict__ qb, const bf16_t* __restrict__ kb, const bf16_t* __restrict__ vtb)
{
    extern __shared__ char smem[];
    bf16_t* Ks = (bf16_t*)smem;                 // [64][512], 16B chunk ^ (row&7)
    bf16_t* Vs = (bf16_t*)(smem + 65536);       // [512][64], 16B chunk ^ (e&7)
    char* PB = smem + 131072;                   // [64 q][64 k] bf16, 8B gran ^ ((q&7)<<1)
    float* pmaxB = (float*)(smem + 139264);     // [2][2][64]
    float* psumB = (float*)(smem + 140288);     // [2][2][64]

    const int bid = blockIdx.x;
    const int xcd = bid & 7, idx = bid >> 3;
    const int qt = idx & 15, bhl = idx >> 4;
    const int bh = xcd * 8 + bhl;
    const int b = bh >> 3, h = bh & 7;
    const int q0 = qt * 64;
    const int tid = threadIdx.x, lane = tid & 63, wid = tid >> 6;
    const int laneq = lane & 15, lx = lane & 7, lg = lane >> 4;
    const int wk = wid >> 2, wq = wid & 3;      // S role
    const int we = wid & 3, wq2 = wid >> 2;     // PV role

    // ---- prologue: stage K(0); load Q frags to registers
#pragma unroll
    for (int r = 0; r < 8; ++r) {
        const int row = r * 8 + wid;
        gload_lds16(kb + ((long long)(b * 1024 + row) * 8 + h) * 512 + ((lane ^ (row & 7)) << 3),
                    Ks + row * 512);
    }
    const int qi = wq * 16 + laneq;
    bf16x8 qfrag[16];
    {
        const bf16_t* qrow = qb + ((long long)(b * 1024 + q0 + qi) * 8 + h) * 512 + lg * 8;
#pragma unroll
        for (int ks = 0; ks < 16; ++ks) qfrag[ks] = *reinterpret_cast<const bf16x8*>(qrow + ks * 32);
    }
    f32x4 accA[8], accB[8];
#pragma unroll
    for (int e = 0; e < 8; ++e) { accA[e] = (f32x4){0.f,0.f,0.f,0.f}; accB[e] = (f32x4){0.f,0.f,0.f,0.f}; }
    float mS = 0.f, mPA = 0.f, mPB = 0.f, lA = 0.f, lB = 0.f;
    const int rA0 = wk * 32 + laneq, rA1 = rA0 + 16;
    const int qA = wq2 * 32 + laneq, qB = qA + 16;
    const int qx = (qi & 7) << 1;
    const int qxA = (qA & 7) << 1, qxB = (qB & 7) << 1;
    __syncthreads();

    for (int t = 0; t < 16; ++t) {
        const int kv0 = t * 64;
        // (a) issue V(t) staging — hidden under S-phase
#pragma unroll
        for (int r = 0; r < 8; ++r) {
            const int e = r * 64 + wid * 8 + (lane >> 3);
            gload_lds16(vtb + ((long long)bh * 512 + e) * 1024 + kv0 + ((lx ^ (e & 7)) << 3),
                        Vs + (r * 64 + wid * 8) * 64);
        }
        // (b) S-phase: S^T = K · Q^T
        f32x4 s0 = (f32x4){0.f,0.f,0.f,0.f}, s1 = (f32x4){0.f,0.f,0.f,0.f};
        const char* KsB = (const char*)Ks;
        __builtin_amdgcn_s_setprio(1);
#pragma unroll
        for (int ks = 0; ks < 16; ++ks) {
            const int co = ((ks * 4 + lg) ^ lx) << 4;
            bf16x8 a0 = *(const bf16x8*)(KsB + rA0 * 1024 + co);
            bf16x8 a1 = *(const bf16x8*)(KsB + rA1 * 1024 + co);
            s0 = __builtin_amdgcn_mfma_f32_16x16x32_bf16(a0, qfrag[ks], s0, 0, 0, 0);
            s1 = __builtin_amdgcn_mfma_f32_16x16x32_bf16(a1, qfrag[ks], s1, 0, 0, 0);
        }
        __builtin_amdgcn_s_setprio(0);
        // (c) delayed-max P = 2^(f - mS), partial max/sum, write P
        float f[8];
#pragma unroll
        for (int j = 0; j < 4; ++j) { f[j] = s0[j] * SCL; f[4 + j] = s1[j] * SCL; }
        float mloc = f[0];
#pragma unroll
        for (int j = 1; j < 8; ++j) mloc = fmaxf(mloc, f[j]);
        mloc = fmaxf(mloc, __shfl_xor(mloc, 16));
        mloc = fmaxf(mloc, __shfl_xor(mloc, 32));
        float pe[8]; float sl = 0.f;
#pragma unroll
        for (int j = 0; j < 8; ++j) { pe[j] = exp2f(f[j] - mS); sl += pe[j]; }
        sl += __shfl_xor(sl, 16);
        sl += __shfl_xor(sl, 32);
        if (lane < 16) {
            pmaxB[(t & 1) * 128 + wk * 64 + wq * 16 + lane] = mloc;
            psumB[(t & 1) * 128 + wk * 64 + wq * 16 + lane] = sl;
        }
        {
            bf16x4 p0, p1;
#pragma unroll
            for (int j = 0; j < 4; ++j) { p0[j] = (bf16_t)pe[j]; p1[j] = (bf16_t)pe[4 + j]; }
            const int kc0 = wk * 8 + lg, kc1 = kc0 + 4;
            *(bf16x4*)(PB + qi * 128 + ((kc0 ^ qx) << 3)) = p0;
            *(bf16x4*)(PB + qi * 128 + ((kc1 ^ qx) << 3)) = p1;
        }
        __syncthreads();  // (d): V(t)+P+stats ready (compiler drains vmcnt)

        // (e) issue K(t+1) staging — hidden under PV-phase
        if (t < 15) {
#pragma unroll
            for (int r = 0; r < 8; ++r) {
                const int row = r * 8 + wid;
                gload_lds16(kb + ((long long)(b * 1024 + kv0 + 64 + row) * 8 + h) * 512
                                + ((lane ^ (row & 7)) << 3),
                            Ks + row * 512);
            }
        }
        // (f) PV
        const char* VB = (const char*)Vs;
        __builtin_amdgcn_s_setprio(1);
#pragma unroll
        for (int ks2 = 0; ks2 < 2; ++ks2) {
            const int kcp = ks2 * 8 + lg * 2;
            bf16x8 pA = *(const bf16x8*)(PB + qA * 128 + ((kcp ^ qxA) << 3));
            bf16x8 pBv = *(const bf16x8*)(PB + qB * 128 + ((kcp ^ qxB) << 3));
            const int kcv = ks2 * 4 + lg;
#pragma unroll
            for (int ef = 0; ef < 8; ++ef) {
                const int re = we * 128 + ef * 16 + laneq;
                bf16x8 av = *(const bf16x8*)(VB + re * 128 + ((kcv ^ lx) << 4));
                accA[ef] = __builtin_amdgcn_mfma_f32_16x16x32_bf16(av, pA, accA[ef], 0, 0, 0);
                accB[ef] = __builtin_amdgcn_mfma_f32_16x16x32_bf16(av, pBv, accB[ef], 0, 0, 0);
            }
        }
        __builtin_amdgcn_s_setprio(0);
        // stats: accumulate in M(t) units, then rescale to M(t+1)
        {
            const float* pmax_t = pmaxB + (t & 1) * 128;
            const float* psum_t = psumB + (t & 1) * 128;
            mS = fmaxf(mS, fmaxf(pmax_t[qi], pmax_t[64 + qi]));
            lA += psum_t[qA] + psum_t[64 + qA];
            lB += psum_t[qB] + psum_t[64 + qB];
            const float mnA = fmaxf(mPA, fmaxf(pmax_t[qA], pmax_t[64 + qA]));
            const float mnB = fmaxf(mPB, fmaxf(pmax_t[qB], pmax_t[64 + qB]));
            if (__ballot((mnA > mPA) || (mnB > mPB))) {
                const float rA = exp2f(mPA - mnA), rB = exp2f(mPB - mnB);
                lA *= rA; lB *= rB;
#pragma unroll
                for (int e = 0; e < 8; ++e) {
#pragma unroll
                    for (int j = 0; j < 4; ++j) { accA[e][j] *= rA; accB[e][j] *= rB; }
                }
            }
            mPA = mnA; mPB = mnB;
        }
        __syncthreads();  // (g): K(t+1) ready; P/V reads done
    }

    // ---- epilogue: O = acc / l, store over qb
    const float iA = 1.f / lA, iB = 1.f / lB;
#pragma unroll
    for (int ef = 0; ef < 8; ++ef) {
        const int e0 = we * 128 + ef * 16 + lg * 4;
        bf16x4 oA, oB;
#pragma unroll
        for (int j = 0; j < 4; ++j) { oA[j] = (bf16_t)(accA[ef][j] * iA); oB[j] = (bf16_t)(accB[ef][j] * iB); }
        *(bf16x4*)(qb + ((long long)(b * 1024 + q0 + qA) * 8 + h) * 512 + e0) = oA;
        *(bf16x4*)(qb + ((long long)(b * 1024 + q0 + qB) * 8 + h) * 512 + e0) = oB;
    }
}

extern "C" void kernel_launch(void* const* d_in, const int* in_sizes, int n_in,
                              void* d_out, int out_size, void* d_ws, size_t ws_size,
                              hipStream_t stream)
{
    const float* x    = (const float*)d_in[0];
    const float* cond = (const float*)d_in[1];
    const float* g1w  = (const float*)d_in[2];  const float* g1b  = (const float*)d_in[3];
    const float* be1w = (const float*)d_in[4];  const float* be1b = (const float*)d_in[5];
    const float* a1w  = (const float*)d_in[6];  const float* a1b  = (const float*)d_in[7];
    const float* g2w  = (const float*)d_in[8];  const float* g2b  = (const float*)d_in[9];
    const float* be2w = (const float*)d_in[10]; const float* be2b = (const float*)d_in[11];
    const float* a2w  = (const float*)d_in[12]; const float* a2b  = (const float*)d_in[13];
    const float* ln1g = (const float*)d_in[14]; const float* ln1b = (const float*)d_in[15];
    const float* ln2g = (const float*)d_in[16]; const float* ln2b = (const float*)d_in[17];
    const float* wq   = (const float*)d_in[18]; const float* bq   = (const float*)d_in[19];
    const float* wk   = (const float*)d_in[20]; const float* bk   = (const float*)d_in[21];
    const float* wv   = (const float*)d_in[22]; const float* bv   = (const float*)d_in[23];
    const float* lvw  = (const float*)d_in[24]; const float* lvb  = (const float*)d_in[25];
    const float* f1w  = (const float*)d_in[26]; const float* f1b  = (const float*)d_in[27];
    const float* f2w  = (const float*)d_in[28]; const float* f2b  = (const float*)d_in[29];
    (void)in_sizes; (void)n_in; (void)out_size; (void)ws_size;

    // workspace layout (bytes)
    char* w8 = (char*)d_ws;
    float*  mod  = (float*)(w8);                                   //  98304
    bf16_t* wqT  = (bf16_t*)(w8 + 98304);                          // 4096x512 bf16 (wq/wk/wv contiguous)
    bf16_t* lvwT = (bf16_t*)(w8 + 98304 + 3 * 4194304);            // 512x4096
    bf16_t* f1wT = (bf16_t*)(w8 + 98304 + 4 * 4194304);            // 2048x512
    bf16_t* f2wT = (bf16_t*)(w8 + 98304 + 4 * 4194304 + 2097152);  // 512x2048
    bf16_t* ybf  = (bf16_t*)(w8 + 98304 + 4 * 4194304 + 2 * 2097152);           // 8192x512
    bf16_t* qb   = (bf16_t*)(w8 + 98304 + 4 * 4194304 + 2 * 2097152 + 8388608); // (b,s,h,e); O in place
    bf16_t* kb   = qb + 33554432;    // (b,s,h,e)
    bf16_t* vtb  = kb + 33554432;    // V transposed: (b,h,e,s)

    (void)hipFuncSetAttribute((const void*)flash_kernel,
                              hipFuncAttributeMaxDynamicSharedMemorySize, FA_LDS);

    const dim3 blk(256);
    // weights -> bf16 transposed
    wtrans_kernel<<<dim3(128, 16), blk, 0, stream>>>(wq, wqT, 512, 4096);
    wtrans_kernel<<<dim3(128, 16), blk, 0, stream>>>(wk, wqT + 2097152, 512, 4096);
    wtrans_kernel<<<dim3(128, 16), blk, 0, stream>>>(wv, wqT + 2 * 2097152, 512, 4096);
    wtrans_kernel<<<dim3(16, 128), blk, 0, stream>>>(lvw, lvwT, 4096, 512);
    wtrans_kernel<<<dim3(64, 16), blk, 0, stream>>>(f1w, f1wT, 512, 2048);
    wtrans_kernel<<<dim3(16, 64), blk, 0, stream>>>(f2w, f2wT, 2048, 512);
    // modulation signals
    modsig_kernel<<<48, blk, 0, stream>>>(cond, g1w, be1w, a1w, g2w, be2w, a2w,
                                          g1b, be1b, a1b, g2b, be2b, a2b, mod);
    // LN1 + modulate -> y (bf16)
    ln_mod_kernel<<<8192, 128, 0, stream>>>(x, ln1g, ln1b, mod, mod + 4096, ybf);
    // fused QKV projection (V stored transposed)
    gemmqkv_kernel<<<dim3(96, 64), blk, 0, stream>>>(ybf, wqT, bq, bk, bv, qb, vtb);
    // fused flash attention: O overwrites qb
    flash_kernel<<<1024, 512, FA_LDS, stream>>>(qb, kb, vtb);
    // y2 = x + (O @ lvw + lvb) * alpha1 -> d_out (fp32)
    gemm64_kernel<<<dim3(4, 128), blk, 0, stream>>>(qb, lvwT, lvb, (float*)d_out, x, mod + 8192,
        8192, 512, 4096, 4096, 4096);
    // LN2 + modulate -> z (bf16)
    ln_mod_kernel<<<8192, 128, 0, stream>>>((const float*)d_out, ln2g, ln2b,
                                            mod + 12288, mod + 16384, ybf);
    // FFN
    gemm128_kernel<1><<<dim3(16, 64), blk, 0, stream>>>(ybf, f1wT, f1b, qb,
        8192, 2048, 512, 512, 512, 2048);
    gemm64_kernel<<<dim3(4, 128), blk, 0, stream>>>(qb, f2wT, f2b, (float*)d_out,
        (const float*)d_out, mod + 20480,
        8192, 512, 2048, 2048, 2048);
}

// Round 9
// 675.751 us; speedup vs baseline: 1.3399x; 1.0235x over previous
//
#include <hip/hip_runtime.h>
#include <hip/hip_bf16.h>

typedef __bf16 bf16_t;
typedef bf16_t bf16x8 __attribute__((ext_vector_type(8)));
typedef bf16_t bf16x4 __attribute__((ext_vector_type(4)));
typedef float f32x4 __attribute__((ext_vector_type(4)));

typedef const __attribute__((address_space(1))) void GV;
typedef __attribute__((address_space(3))) void LV;

__device__ __forceinline__ void gload_lds16(const bf16_t* gsrc, bf16_t* ldst) {
    __builtin_amdgcn_global_load_lds((GV*)gsrc, (LV*)ldst, 16, 0, 0);
}

// ---------------- weight transpose+convert: in fp32 (K x N) -> out bf16 (N x K)
__global__ __launch_bounds__(256) void wtrans_kernel(const float* __restrict__ in,
                                                     bf16_t* __restrict__ out, int K, int N)
{
    __shared__ float tile[32][33];
    const int n0 = blockIdx.x * 32, k0 = blockIdx.y * 32;
    const int tx = threadIdx.x & 31, ty = threadIdx.x >> 5;  // 32 x 8
#pragma unroll
    for (int i = 0; i < 32; i += 8)
        tile[ty + i][tx] = in[(long long)(k0 + ty + i) * N + n0 + tx];
    __syncthreads();
#pragma unroll
    for (int i = 0; i < 32; i += 8)
        out[(long long)(n0 + ty + i) * K + k0 + tx] = (bf16_t)tile[tx][ty + i];
}

// ---------------- 6 modulation linears on cond: out[(sig*8+b)*512 + n]
__global__ __launch_bounds__(256) void modsig_kernel(
    const float* __restrict__ cond,
    const float* __restrict__ w0, const float* __restrict__ w1, const float* __restrict__ w2,
    const float* __restrict__ w3, const float* __restrict__ w4, const float* __restrict__ w5,
    const float* __restrict__ c0, const float* __restrict__ c1, const float* __restrict__ c2,
    const float* __restrict__ c3, const float* __restrict__ c4, const float* __restrict__ c5,
    float* __restrict__ out)
{
    __shared__ float cs[512];
    const int sig = blockIdx.x >> 3, b = blockIdx.x & 7;
    const float* w; const float* bi;
    switch (sig) {
        case 0: w = w0; bi = c0; break;
        case 1: w = w1; bi = c1; break;
        case 2: w = w2; bi = c2; break;
        case 3: w = w3; bi = c3; break;
        case 4: w = w4; bi = c4; break;
        default: w = w5; bi = c5; break;
    }
    for (int i = threadIdx.x; i < 512; i += 256) cs[i] = cond[b * 512 + i];
    __syncthreads();
    for (int n = threadIdx.x; n < 512; n += 256) {
        float s = bi[n];
        for (int i = 0; i < 512; ++i) s = fmaf(cs[i], w[(long long)i * 512 + n], s);
        out[(long long)(sig * 8 + b) * 512 + n] = s;
    }
}

// ---------------- fused LayerNorm + AdaLN modulate, fp32 -> bf16
__global__ __launch_bounds__(128) void ln_mod_kernel(
    const float* __restrict__ x, const float* __restrict__ g, const float* __restrict__ be,
    const float* __restrict__ gamma, const float* __restrict__ beta, bf16_t* __restrict__ out)
{
    const int row = blockIdx.x;
    const int b = row >> 10;
    const int t = threadIdx.x;
    const float4 v = reinterpret_cast<const float4*>(x + (long long)row * 512)[t];
    float s = v.x + v.y + v.z + v.w;
    float ss = v.x * v.x + v.y * v.y + v.z * v.z + v.w * v.w;
    for (int o = 32; o; o >>= 1) { s += __shfl_xor(s, o); ss += __shfl_xor(ss, o); }
    __shared__ float red[4];
    if ((t & 63) == 0) { red[t >> 6] = s; red[2 + (t >> 6)] = ss; }
    __syncthreads();
    s = red[0] + red[1]; ss = red[2] + red[3];
    const float mu = s * (1.f / 512.f);
    const float rstd = rsqrtf(ss * (1.f / 512.f) - mu * mu + 1e-5f);
    const float4 gv = reinterpret_cast<const float4*>(g)[t];
    const float4 bv = reinterpret_cast<const float4*>(be)[t];
    const float4 ga = reinterpret_cast<const float4*>(gamma + b * 512)[t];
    const float4 bb = reinterpret_cast<const float4*>(beta + b * 512)[t];
    bf16x4 ov;
    ov[0] = (bf16_t)(((v.x - mu) * rstd * gv.x + bv.x) * (1.f + ga.x) + bb.x);
    ov[1] = (bf16_t)(((v.y - mu) * rstd * gv.y + bv.y) * (1.f + ga.y) + bb.y);
    ov[2] = (bf16_t)(((v.z - mu) * rstd * gv.z + bv.z) * (1.f + ga.z) + bb.z);
    ov[3] = (bf16_t)(((v.w - mu) * rstd * gv.w + bv.w) * (1.f + ga.w) + bb.w);
    reinterpret_cast<bf16x4*>(out + (long long)row * 512)[t] = ov;
}

// ---------------- 128x128x64 bf16 MFMA GEMM (BK=64), C = A * B^T, XCD-swizzled grid
// EPI 0: bf16 store (+bias)  EPI 1: relu->bf16 (+bias)
template <int EPI>
__global__ __launch_bounds__(256) void gemm128_kernel(
    const bf16_t* __restrict__ A, const bf16_t* __restrict__ B,
    const float* __restrict__ bias, void* Cout,
    int M, int N, int K, int lda, int ldb, int ldc)
{
    const int nbx = gridDim.x;
    const int lin = blockIdx.y * nbx + blockIdx.x;
    const int cpx = (nbx * gridDim.y) >> 3;
    const int swz = (lin & 7) * cpx + (lin >> 3);
    const int m0 = (swz / nbx) * 128, n0 = (swz % nbx) * 128;
    const int tid = threadIdx.x, lane = tid & 63, wid = tid >> 6;
    const int wr = wid >> 1, wc = wid & 1;

    __shared__ bf16_t As[8192];
    __shared__ bf16_t Bs[8192];

    f32x4 acc[4][4];
#pragma unroll
    for (int m = 0; m < 4; ++m)
#pragma unroll
        for (int n = 0; n < 4; ++n) acc[m][n] = (f32x4){0.f, 0.f, 0.f, 0.f};

    const int r8 = lane >> 3;
    const int lc = (lane & 7) ^ r8;
    long long aOff[4], bOff[4];
#pragma unroll
    for (int i = 0; i < 4; ++i) {
        const int row = i * 32 + wid * 8 + r8;
        aOff[i] = (long long)(m0 + row) * lda + lc * 8;
        bOff[i] = (long long)(n0 + row) * ldb + lc * 8;
    }

    const int frow = lane & 15, lg = lane >> 4;
    const int p0 = lg ^ (frow & 7);

    for (int kt = 0; kt < K; kt += 64) {
#pragma unroll
        for (int i = 0; i < 4; ++i) gload_lds16(A + aOff[i] + kt, As + i * 2048 + wid * 512);
#pragma unroll
        for (int i = 0; i < 4; ++i) gload_lds16(B + bOff[i] + kt, Bs + i * 2048 + wid * 512);
        __syncthreads();
        __builtin_amdgcn_s_setprio(1);
#pragma unroll
        for (int kk = 0; kk < 2; ++kk) {
            const int pc = p0 ^ (kk << 2);
            bf16x8 af[4], bfv[4];
#pragma unroll
            for (int m = 0; m < 4; ++m)
                af[m] = *reinterpret_cast<const bf16x8*>(As + (wr * 64 + m * 16 + frow) * 64 + pc * 8);
#pragma unroll
            for (int n = 0; n < 4; ++n)
                bfv[n] = *reinterpret_cast<const bf16x8*>(Bs + (wc * 64 + n * 16 + frow) * 64 + pc * 8);
#pragma unroll
            for (int m = 0; m < 4; ++m)
#pragma unroll
                for (int n = 0; n < 4; ++n)
                    acc[m][n] = __builtin_amdgcn_mfma_f32_16x16x32_bf16(af[m], bfv[n], acc[m][n], 0, 0, 0);
        }
        __builtin_amdgcn_s_setprio(0);
        __syncthreads();
    }

#pragma unroll
    for (int m = 0; m < 4; ++m) {
        const int gm = m0 + wr * 64 + m * 16 + ((lane >> 4) << 2);
#pragma unroll
        for (int n = 0; n < 4; ++n) {
            const int gn = n0 + wc * 64 + n * 16 + (lane & 15);
            const float bb = bias ? bias[gn] : 0.f;
#pragma unroll
            for (int j = 0; j < 4; ++j) {
                const float v = acc[m][n][j] + bb;
                const int gmj = gm + j;
                if (EPI == 0) {
                    ((bf16_t*)Cout)[(long long)gmj * ldc + gn] = (bf16_t)v;
                } else {
                    ((bf16_t*)Cout)[(long long)gmj * ldc + gn] = (bf16_t)fmaxf(v, 0.f);
                }
            }
        }
    }
}

// ---------------- fused QKV GEMM (BK=64, XCD-swizzled): B = [wqT;wkT;wvT] (12288x512)
// n-section 0 -> qb, 1 -> kb, 2 -> vtb (transposed-V (b,h,e,s) layout)
__global__ __launch_bounds__(256) void gemmqkv_kernel(
    const bf16_t* __restrict__ A, const bf16_t* __restrict__ B,
    const float* __restrict__ bq, const float* __restrict__ bk, const float* __restrict__ bv,
    bf16_t* __restrict__ qkv, bf16_t* __restrict__ vtb)
{
    const int lin = blockIdx.y * 96 + blockIdx.x;
    const int swz = (lin & 7) * 768 + (lin >> 3);
    const int m0 = (swz / 96) * 128, n0 = (swz % 96) * 128;
    const int sec = n0 >> 12;
    const float* bias = (sec == 0) ? bq : ((sec == 1) ? bk : bv);
    const int tid = threadIdx.x, lane = tid & 63, wid = tid >> 6;
    const int wr = wid >> 1, wc = wid & 1;

    __shared__ bf16_t As[8192];
    __shared__ bf16_t Bs[8192];

    f32x4 acc[4][4];
#pragma unroll
    for (int m = 0; m < 4; ++m)
#pragma unroll
        for (int n = 0; n < 4; ++n) acc[m][n] = (f32x4){0.f, 0.f, 0.f, 0.f};

    const int r8 = lane >> 3;
    const int lc = (lane & 7) ^ r8;
    long long aOff[4], bOff[4];
#pragma unroll
    for (int i = 0; i < 4; ++i) {
        const int row = i * 32 + wid * 8 + r8;
        aOff[i] = (long long)(m0 + row) * 512 + lc * 8;
        bOff[i] = (long long)(n0 + row) * 512 + lc * 8;
    }

    const int frow = lane & 15, lg = lane >> 4;
    const int p0 = lg ^ (frow & 7);

    for (int kt = 0; kt < 512; kt += 64) {
#pragma unroll
        for (int i = 0; i < 4; ++i) gload_lds16(A + aOff[i] + kt, As + i * 2048 + wid * 512);
#pragma unroll
        for (int i = 0; i < 4; ++i) gload_lds16(B + bOff[i] + kt, Bs + i * 2048 + wid * 512);
        __syncthreads();
        __builtin_amdgcn_s_setprio(1);
#pragma unroll
        for (int kk = 0; kk < 2; ++kk) {
            const int pc = p0 ^ (kk << 2);
            bf16x8 af[4], bfv[4];
#pragma unroll
            for (int m = 0; m < 4; ++m)
                af[m] = *reinterpret_cast<const bf16x8*>(As + (wr * 64 + m * 16 + frow) * 64 + pc * 8);
#pragma unroll
            for (int n = 0; n < 4; ++n)
                bfv[n] = *reinterpret_cast<const bf16x8*>(Bs + (wc * 64 + n * 16 + frow) * 64 + pc * 8);
#pragma unroll
            for (int m = 0; m < 4; ++m)
#pragma unroll
                for (int n = 0; n < 4; ++n)
                    acc[m][n] = __builtin_amdgcn_mfma_f32_16x16x32_bf16(af[m], bfv[n], acc[m][n], 0, 0, 0);
        }
        __builtin_amdgcn_s_setprio(0);
        __syncthreads();
    }

#pragma unroll
    for (int m = 0; m < 4; ++m) {
        const int gm = m0 + wr * 64 + m * 16 + ((lane >> 4) << 2);
#pragma unroll
        for (int n = 0; n < 4; ++n) {
            const int gn = n0 + wc * 64 + n * 16 + (lane & 15);
            const int gnl = gn & 4095;
            const float bb = bias[gnl];
#pragma unroll
            for (int j = 0; j < 4; ++j) {
                const float v = acc[m][n][j] + bb;
                const int gmj = gm + j;
                if (sec < 2) {
                    qkv[(long long)sec * 33554432 + (long long)gmj * 4096 + gnl] = (bf16_t)v;
                } else {
                    const long long ci =
                        (long long)(((gmj >> 10) * 8 + (gnl >> 9)) * 512 + (gnl & 511)) * 1024 + (gmj & 1023);
                    vtb[ci] = (bf16_t)v;
                }
            }
        }
    }
}

// ---------------- 64x128x64 GEMM (BK=64, XCD-swizzled), out = resid + (acc+bias)*alpha
__global__ __launch_bounds__(256) void gemm64_kernel(
    const bf16_t* __restrict__ A, const bf16_t* __restrict__ B,
    const float* __restrict__ bias, float* __restrict__ Cout,
    const float* __restrict__ resid, const float* __restrict__ alpha,
    int M, int N, int K, int lda, int ldb)
{
    const int nbx = gridDim.x;
    const int lin = blockIdx.y * nbx + blockIdx.x;
    const int cpx = (nbx * gridDim.y) >> 3;
    const int swz = (lin & 7) * cpx + (lin >> 3);
    const int m0 = (swz / nbx) * 64, n0 = (swz % nbx) * 128;
    const int tid = threadIdx.x, lane = tid & 63, wid = tid >> 6;
    const int wr = wid >> 1, wc = wid & 1;

    __shared__ bf16_t As[4096];
    __shared__ bf16_t Bs[8192];

    f32x4 acc[2][4];
#pragma unroll
    for (int m = 0; m < 2; ++m)
#pragma unroll
        for (int n = 0; n < 4; ++n) acc[m][n] = (f32x4){0.f, 0.f, 0.f, 0.f};

    const int r8 = lane >> 3;
    const int lc = (lane & 7) ^ r8;
    long long aOff[2], bOff[4];
#pragma unroll
    for (int i = 0; i < 2; ++i)
        aOff[i] = (long long)(m0 + i * 32 + wid * 8 + r8) * lda + lc * 8;
#pragma unroll
    for (int i = 0; i < 4; ++i)
        bOff[i] = (long long)(n0 + i * 32 + wid * 8 + r8) * ldb + lc * 8;

    const int frow = lane & 15, lg = lane >> 4;
    const int p0 = lg ^ (frow & 7);

    for (int kt = 0; kt < K; kt += 64) {
#pragma unroll
        for (int i = 0; i < 2; ++i) gload_lds16(A + aOff[i] + kt, As + i * 2048 + wid * 512);
#pragma unroll
        for (int i = 0; i < 4; ++i) gload_lds16(B + bOff[i] + kt, Bs + i * 2048 + wid * 512);
        __syncthreads();
        __builtin_amdgcn_s_setprio(1);
#pragma unroll
        for (int kk = 0; kk < 2; ++kk) {
            const int pc = p0 ^ (kk << 2);
            bf16x8 af[2], bfv[4];
#pragma unroll
            for (int m = 0; m < 2; ++m)
                af[m] = *reinterpret_cast<const bf16x8*>(As + (wr * 32 + m * 16 + frow) * 64 + pc * 8);
#pragma unroll
            for (int n = 0; n < 4; ++n)
                bfv[n] = *reinterpret_cast<const bf16x8*>(Bs + (wc * 64 + n * 16 + frow) * 64 + pc * 8);
#pragma unroll
            for (int m = 0; m < 2; ++m)
#pragma unroll
                for (int n = 0; n < 4; ++n)
                    acc[m][n] = __builtin_amdgcn_mfma_f32_16x16x32_bf16(af[m], bfv[n], acc[m][n], 0, 0, 0);
        }
        __builtin_amdgcn_s_setprio(0);
        __syncthreads();
    }

#pragma unroll
    for (int m = 0; m < 2; ++m) {
        const int gm = m0 + wr * 32 + m * 16 + ((lane >> 4) << 2);
#pragma unroll
        for (int n = 0; n < 4; ++n) {
            const int gn = n0 + wc * 64 + n * 16 + (lane & 15);
            const float bb = bias[gn];
#pragma unroll
            for (int j = 0; j < 4; ++j) {
                const int gmj = gm + j;
                const long long ci = (long long)gmj * 512 + gn;
                Cout[ci] = resid[ci] + (acc[m][n][j] + bb) * alpha[(gmj >> 10) * 512 + gn];
            }
        }
    }
}

// ---------------- fused flash attention v6: QBLK=32, KVBLK=32, 4 waves, 2 blocks/CU
// Same 2-barrier pipeline as v2 (V(t)-issue || S; K(t+1)-issue || PV), but 256-thread
// blocks with 68.6 KB LDS so TWO independent blocks co-reside per CU and cover each
// other's barrier/drain stalls. Math identical to v2 (delayed running max).
#define FA_LDS 68608
#define SCL 0.04508422132207354f   /* (1/32) * log2(e) */
__global__ __launch_bounds__(256, 2) void flash_kernel(
    bf16_t* __restrict__ qb, const bf16_t* __restrict__ kb, const bf16_t* __restrict__ vtb)
{
    extern __shared__ char smem[];
    bf16_t* Ks = (bf16_t*)smem;               // [32][512], chunk16 ^ (row&7)
    bf16_t* Vs = (bf16_t*)(smem + 32768);     // [512][32], chunk16 ^ (e&3)
    char* PB = smem + 65536;                  // [32 q][32 k]; granule g at chunk (g>>1)^(q&3), pos g&1
    float* pmaxB = (float*)(smem + 67584);    // [2][2][32]
    float* psumB = (float*)(smem + 68096);    // [2][2][32]

    const int bid = blockIdx.x;
    const int xcd = bid & 7, idx = bid >> 3;
    const int qt = idx & 31, bhl = idx >> 5;
    const int bh = xcd * 8 + bhl;
    const int b = bh >> 3, h = bh & 7;
    const int q0 = qt * 32;
    const int tid = threadIdx.x, lane = tid & 63, wid = tid >> 6;  // 4 waves
    const int laneq = lane & 15, lx = lane & 7, lg = lane >> 4;
    const int wk = wid >> 1, wq = wid & 1;    // S role: k-half, q-half
    const int we = wid;                       // PV role: e-quarter

    // ---- prologue: stage K(0); Q frags to registers
#pragma unroll
    for (int r = 0; r < 8; ++r) {
        const int row = r * 4 + wid;
        gload_lds16(kb + ((long long)(b * 1024 + row) * 8 + h) * 512 + ((lane ^ (row & 7)) << 3),
                    Ks + row * 512);
    }
    const int qi = wq * 16 + laneq;
    bf16x8 qfrag[16];
    {
        const bf16_t* qrow = qb + ((long long)(b * 1024 + q0 + qi) * 8 + h) * 512 + lg * 8;
#pragma unroll
        for (int ks = 0; ks < 16; ++ks) qfrag[ks] = *reinterpret_cast<const bf16x8*>(qrow + ks * 32);
    }
    f32x4 accA[8], accB[8];
#pragma unroll
    for (int e = 0; e < 8; ++e) { accA[e] = (f32x4){0.f,0.f,0.f,0.f}; accB[e] = (f32x4){0.f,0.f,0.f,0.f}; }
    float mS = 0.f, mPA = 0.f, mPB = 0.f, lA = 0.f, lB = 0.f;
    const int rA = wk * 16 + laneq;           // K LDS row for S-phase
    const int qA = laneq, qB = laneq + 16;    // PV-role q rows
    __syncthreads();

    for (int t = 0; t < 32; ++t) {
        // (a) issue V(t) staging — hidden under S-phase
#pragma unroll
        for (int r = 0; r < 8; ++r) {
            const int e0 = (r * 4 + wid) * 16;
            const int e = e0 + (lane >> 2);
            gload_lds16(vtb + ((long long)bh * 512 + e) * 1024 + t * 32 + (((lane & 3) ^ (e & 3)) << 3),
                        Vs + e0 * 32);
        }
        // (b) S-phase: S^T tile = K · Q^T (16 MFMAs)
        f32x4 s0 = (f32x4){0.f, 0.f, 0.f, 0.f};
        const char* KsB = (const char*)Ks;
        __builtin_amdgcn_s_setprio(1);
#pragma unroll
        for (int ks = 0; ks < 16; ++ks) {
            const int co = (((ks * 4 + lg) ^ lx) << 4);
            bf16x8 a0 = *(const bf16x8*)(KsB + rA * 1024 + co);
            s0 = __builtin_amdgcn_mfma_f32_16x16x32_bf16(a0, qfrag[ks], s0, 0, 0, 0);
        }
        __builtin_amdgcn_s_setprio(0);
        // (c) delayed-max softmax partials + P write
        float f[4], pe[4];
#pragma unroll
        for (int j = 0; j < 4; ++j) f[j] = s0[j] * SCL;
        float mloc = fmaxf(fmaxf(f[0], f[1]), fmaxf(f[2], f[3]));
        mloc = fmaxf(mloc, __shfl_xor(mloc, 16));
        mloc = fmaxf(mloc, __shfl_xor(mloc, 32));
        float sl = 0.f;
#pragma unroll
        for (int j = 0; j < 4; ++j) { pe[j] = exp2f(f[j] - mS); sl += pe[j]; }
        sl += __shfl_xor(sl, 16);
        sl += __shfl_xor(sl, 32);
        if (lane < 16) {
            pmaxB[(t & 1) * 64 + wk * 32 + wq * 16 + lane] = mloc;
            psumB[(t & 1) * 64 + wk * 32 + wq * 16 + lane] = sl;
        }
        {
            bf16x4 p;
#pragma unroll
            for (int j = 0; j < 4; ++j) p[j] = (bf16_t)pe[j];
            const int g = wk * 4 + lg;  // granule (4 bf16) index along k
            *(bf16x4*)(PB + qi * 64 + (((g >> 1) ^ (qi & 3)) << 4) + ((g & 1) << 3)) = p;
        }
        __syncthreads();  // (d): V(t)+P+stats ready (vmcnt drained)

        // (e) issue K(t+1) staging — hidden under PV-phase
        if (t < 31) {
#pragma unroll
            for (int r = 0; r < 8; ++r) {
                const int row = r * 4 + wid;
                gload_lds16(kb + ((long long)(b * 1024 + t * 32 + 32 + row) * 8 + h) * 512
                                + ((lane ^ (row & 7)) << 3),
                            Ks + row * 512);
            }
        }
        // (f) PV: 16 MFMAs (K=32 in one MFMA per e-tile)
        const char* VB = (const char*)Vs;
        bf16x8 pA = *(const bf16x8*)(PB + qA * 64 + ((lg ^ (qA & 3)) << 4));
        bf16x8 pBv = *(const bf16x8*)(PB + qB * 64 + ((lg ^ (qB & 3)) << 4));
        __builtin_amdgcn_s_setprio(1);
#pragma unroll
        for (int ef = 0; ef < 8; ++ef) {
            const int re = we * 128 + ef * 16 + laneq;
            bf16x8 av = *(const bf16x8*)(VB + re * 64 + ((lg ^ (re & 3)) << 4));
            accA[ef] = __builtin_amdgcn_mfma_f32_16x16x32_bf16(av, pA, accA[ef], 0, 0, 0);
            accB[ef] = __builtin_amdgcn_mfma_f32_16x16x32_bf16(av, pBv, accB[ef], 0, 0, 0);
        }
        __builtin_amdgcn_s_setprio(0);
        // stats: accumulate in old-max units, then rescale to new max
        {
            const float* pmax_t = pmaxB + (t & 1) * 64;
            const float* psum_t = psumB + (t & 1) * 64;
            mS = fmaxf(mS, fmaxf(pmax_t[qi], pmax_t[32 + qi]));
            lA += psum_t[qA] + psum_t[32 + qA];
            lB += psum_t[qB] + psum_t[32 + qB];
            const float mnA = fmaxf(mPA, fmaxf(pmax_t[qA], pmax_t[32 + qA]));
            const float mnB = fmaxf(mPB, fmaxf(pmax_t[qB], pmax_t[32 + qB]));
            if (__ballot((mnA > mPA) || (mnB > mPB))) {
                const float rsA = exp2f(mPA - mnA), rsB = exp2f(mPB - mnB);
                lA *= rsA; lB *= rsB;
#pragma unroll
                for (int e = 0; e < 8; ++e) {
#pragma unroll
                    for (int j = 0; j < 4; ++j) { accA[e][j] *= rsA; accB[e][j] *= rsB; }
                }
            }
            mPA = mnA; mPB = mnB;
        }
        __syncthreads();  // (g): K(t+1) ready; P/V reads done
    }

    // ---- epilogue: O = acc / l, store over qb
    const float iA = 1.f / lA, iB = 1.f / lB;
#pragma unroll
    for (int ef = 0; ef < 8; ++ef) {
        const int e0 = we * 128 + ef * 16 + lg * 4;
        bf16x4 oA, oB;
#pragma unroll
        for (int j = 0; j < 4; ++j) { oA[j] = (bf16_t)(accA[ef][j] * iA); oB[j] = (bf16_t)(accB[ef][j] * iB); }
        *(bf16x4*)(qb + ((long long)(b * 1024 + q0 + qA) * 8 + h) * 512 + e0) = oA;
        *(bf16x4*)(qb + ((long long)(b * 1024 + q0 + qB) * 8 + h) * 512 + e0) = oB;
    }
}

extern "C" void kernel_launch(void* const* d_in, const int* in_sizes, int n_in,
                              void* d_out, int out_size, void* d_ws, size_t ws_size,
                              hipStream_t stream)
{
    const float* x    = (const float*)d_in[0];
    const float* cond = (const float*)d_in[1];
    const float* g1w  = (const float*)d_in[2];  const float* g1b  = (const float*)d_in[3];
    const float* be1w = (const float*)d_in[4];  const float* be1b = (const float*)d_in[5];
    const float* a1w  = (const float*)d_in[6];  const float* a1b  = (const float*)d_in[7];
    const float* g2w  = (const float*)d_in[8];  const float* g2b  = (const float*)d_in[9];
    const float* be2w = (const float*)d_in[10]; const float* be2b = (const float*)d_in[11];
    const float* a2w  = (const float*)d_in[12]; const float* a2b  = (const float*)d_in[13];
    const float* ln1g = (const float*)d_in[14]; const float* ln1b = (const float*)d_in[15];
    const float* ln2g = (const float*)d_in[16]; const float* ln2b = (const float*)d_in[17];
    const float* wq   = (const float*)d_in[18]; const float* bq   = (const float*)d_in[19];
    const float* wk   = (const float*)d_in[20]; const float* bk   = (const float*)d_in[21];
    const float* wv   = (const float*)d_in[22]; const float* bv   = (const float*)d_in[23];
    const float* lvw  = (const float*)d_in[24]; const float* lvb  = (const float*)d_in[25];
    const float* f1w  = (const float*)d_in[26]; const float* f1b  = (const float*)d_in[27];
    const float* f2w  = (const float*)d_in[28]; const float* f2b  = (const float*)d_in[29];
    (void)in_sizes; (void)n_in; (void)out_size; (void)ws_size;

    // workspace layout (bytes)
    char* w8 = (char*)d_ws;
    float*  mod  = (float*)(w8);                                   //  98304
    bf16_t* wqT  = (bf16_t*)(w8 + 98304);                          // 4096x512 bf16 (wq/wk/wv contiguous)
    bf16_t* lvwT = (bf16_t*)(w8 + 98304 + 3 * 4194304);            // 512x4096
    bf16_t* f1wT = (bf16_t*)(w8 + 98304 + 4 * 4194304);            // 2048x512
    bf16_t* f2wT = (bf16_t*)(w8 + 98304 + 4 * 4194304 + 2097152);  // 512x2048
    bf16_t* ybf  = (bf16_t*)(w8 + 98304 + 4 * 4194304 + 2 * 2097152);           // 8192x512
    bf16_t* qb   = (bf16_t*)(w8 + 98304 + 4 * 4194304 + 2 * 2097152 + 8388608); // (b,s,h,e); O in place
    bf16_t* kb   = qb + 33554432;    // (b,s,h,e)
    bf16_t* vtb  = kb + 33554432;    // V transposed: (b,h,e,s)

    (void)hipFuncSetAttribute((const void*)flash_kernel,
                              hipFuncAttributeMaxDynamicSharedMemorySize, FA_LDS);

    const dim3 blk(256);
    // weights -> bf16 transposed
    wtrans_kernel<<<dim3(128, 16), blk, 0, stream>>>(wq, wqT, 512, 4096);
    wtrans_kernel<<<dim3(128, 16), blk, 0, stream>>>(wk, wqT + 2097152, 512, 4096);
    wtrans_kernel<<<dim3(128, 16), blk, 0, stream>>>(wv, wqT + 2 * 2097152, 512, 4096);
    wtrans_kernel<<<dim3(16, 128), blk, 0, stream>>>(lvw, lvwT, 4096, 512);
    wtrans_kernel<<<dim3(64, 16), blk, 0, stream>>>(f1w, f1wT, 512, 2048);
    wtrans_kernel<<<dim3(16, 64), blk, 0, stream>>>(f2w, f2wT, 2048, 512);
    // modulation signals
    modsig_kernel<<<48, blk, 0, stream>>>(cond, g1w, be1w, a1w, g2w, be2w, a2w,
                                          g1b, be1b, a1b, g2b, be2b, a2b, mod);
    // LN1 + modulate -> y (bf16)
    ln_mod_kernel<<<8192, 128, 0, stream>>>(x, ln1g, ln1b, mod, mod + 4096, ybf);
    // fused QKV projection (V stored transposed)
    gemmqkv_kernel<<<dim3(96, 64), blk, 0, stream>>>(ybf, wqT, bq, bk, bv, qb, vtb);
    // fused flash attention: O overwrites qb
    flash_kernel<<<2048, 256, FA_LDS, stream>>>(qb, kb, vtb);
    // y2 = x + (O @ lvw + lvb) * alpha1 -> d_out (fp32)
    gemm64_kernel<<<dim3(4, 128), blk, 0, stream>>>(qb, lvwT, lvb, (float*)d_out, x, mod + 8192,
        8192, 512, 4096, 4096, 4096);
    // LN2 + modulate -> z (bf16)
    ln_mod_kernel<<<8192, 128, 0, stream>>>((const float*)d_out, ln2g, ln2b,
                                            mod + 12288, mod + 16384, ybf);
    // FFN
    gemm128_kernel<1><<<dim3(16, 64), blk, 0, stream>>>(ybf, f1wT, f1b, qb,
        8192, 2048, 512, 512, 512, 2048);
    gemm64_kernel<<<dim3(4, 128), blk, 0, stream>>>(qb, f2wT, f2b, (float*)d_out,
        (const float*)d_out, mod + 20480,
        8192, 512, 2048, 2048, 2048);
}